// Round 7
// baseline (530.769 us; speedup 1.0000x reference)
//
#include <hip/hip_runtime.h>

typedef __attribute__((ext_vector_type(8))) short bf16x8;
typedef __attribute__((ext_vector_type(4))) float f32x4;

// ---------- helpers ----------
__device__ __forceinline__ unsigned short bf16_rne(float x){
  unsigned int u = __float_as_uint(x);
  unsigned int r = (u + 0x7FFFu + ((u >> 16) & 1u)) >> 16;
  return (unsigned short)r;
}
__device__ __forceinline__ float bf16_tof(unsigned short h){
  return __uint_as_float(((unsigned int)h) << 16);
}
__device__ __forceinline__ void split2(float x, unsigned short &hi, unsigned short &lo){
  hi = bf16_rne(x);
  lo = bf16_rne(x - bf16_tof(hi));
}
__device__ __forceinline__ void gload_lds16(const void* g, void* l){
  __builtin_amdgcn_global_load_lds((const __attribute__((address_space(1))) void*)g,
                                   (__attribute__((address_space(3))) void*)l, 16, 0, 0);
}
#define VM(N)    asm volatile("s_waitcnt vmcnt(" #N ")" ::: "memory")
#define LGKM(N)  do { asm volatile("s_waitcnt lgkmcnt(" #N ")" ::: "memory"); \
                      __builtin_amdgcn_sched_barrier(0); } while(0)
#define LGKM0()  LGKM(0)
#define BAR()    do { __builtin_amdgcn_s_barrier(); \
                      __builtin_amdgcn_sched_barrier(0); } while(0)

// K-index remap for the 3-term split expressed as a K=3072 concat GEMM.
// MAP 0: identity. MAP 1: blocks [hi|lo|hi]. MAP 2: blocks [hi|hi|lo].
template<int MAP>
__device__ __forceinline__ int kmap(int k){
  if (MAP == 1) return (k < 2048) ? k : (k - 2048);
  if (MAP == 2) return (k < 1024) ? k : (k - 1024);
  return k;
}

// ============================================================================
// 256x256 GEMM, BK=64, 512 threads (8 waves 2x4), 2 LDS slots x 64KB.
// Read-early phase pipeline with CORRECT cross-wave certification:
//   a region may be ds_read only AFTER a barrier which every wave crossed
//   AFTER executing the VM gate that retires that region's gloads.
// Stage quarters (2 gloads each): q0=A.k0, q1=B.k0, q2=B.k1, q3=A.k1;
// q_p(t+1) issued in phase p of tile t.
// Gates (per wave FIFO, pre-BAR):
//   G2 @P0(t): VM(2) retires q2,q3(t)   {out: q2,q3(t), q0(t+1)}
//     -> certifies A.k1/B.k1(sb) for READ_P2@P1(t), READ_P3@P2(t)
//   G1 @P2(t): VM(2) retires q0,q1(t+1) {out: q0,q1,q2(t+1)}
//     -> certifies A.k0/B.k0(nb) for READ_P0(nb)@P3(t)
// Frag reads issued ONE phase before use; pre-MFMA wait = counted LGKM:
//   issue R0@P3(t-1)[8], R1@P0[4], R2@P1[8], R3@P2[4] ->
//   LGKM 4/8/4/8 retires exactly the consumed set.
// WAR: each region's last ds_read retires (via the consuming LGKM, pre-BAR)
// >=2 barriers before its overwrite. XOR-swizzled LDS (0 conflicts, R2).
// EPI 0: split hi/lo write (y). EPI 1: bf16(acc+bias[col])^T write (featsT).
// ============================================================================
template<int MAPA, int MAPB, int NK, int EPI>
__global__ __launch_bounds__(512, 2) void k_gemm256(
    const unsigned short* __restrict__ A, const unsigned short* __restrict__ B,
    unsigned short* __restrict__ outp, const float* __restrict__ bias)
{
  __shared__ __align__(16) unsigned short lds_u[65536];   // 128 KiB
  char* ldsb = (char*)lds_u;

  int bid = blockIdx.x;                 // XCD-aware swizzle (grid 512 % 8 == 0)
  bid = (bid & 7) * 64 + (bid >> 3);
  const int bm = bid >> 2, bn = bid & 3;

  const int tid  = threadIdx.x;
  const int w    = tid >> 6;
  const int lane = tid & 63;
  const int wm   = w >> 2;              // 0..1
  const int wn   = w & 3;               // 0..3
  const int l15  = lane & 15;
  const int lg   = lane >> 4;

  // staging source map (inverse swizzle), 2 chunks per 16K region
  int srow[2], slg[2];
#pragma unroll
  for (int j = 0; j < 2; j++){
    int o16 = j * 512 + tid;
    int p = o16 >> 3, s = o16 & 7;
    int q = s ^ (p & 7);
    srow[j] = 2 * p + (q >> 2);
    slg[j]  = q & 3;
  }
  const unsigned short* aS0 = A + (size_t)(bm * 256 + srow[0]) * 2048 + slg[0] * 8;
  const unsigned short* aS1 = A + (size_t)(bm * 256 + srow[1]) * 2048 + slg[1] * 8;
  const unsigned short* bS0 = B + (size_t)(bn * 256 + srow[0]) * 2048 + slg[0] * 8;
  const unsigned short* bS1 = B + (size_t)(bn * 256 + srow[1]) * 2048 + slg[1] * 8;

  const int sA   = (((l15 & 1) << 2) | lg) ^ ((l15 >> 1) & 7);
  const int rps  = (l15 >> 1) * 128 + sA * 16;

  f32x4 acc[8][4];
  f32x4 zero = {0.f, 0.f, 0.f, 0.f};
#pragma unroll
  for (int m = 0; m < 8; m++)
#pragma unroll
    for (int n = 0; n < 4; n++) acc[m][n] = zero;

  auto STAGE_Q = [&](int t, int q){
    char* slot = ldsb + (size_t)(t & 1) * 65536;
    const int kbA = kmap<MAPA>(t * 64);
    const int kbB = kmap<MAPB>(t * 64);
    if (q == 0){
      gload_lds16(aS0 + kbA,      slot +         w * 1024);
      gload_lds16(aS1 + kbA,      slot +  8192 + w * 1024);
    } else if (q == 1){
      gload_lds16(bS0 + kbB,      slot + 32768 + w * 1024);
      gload_lds16(bS1 + kbB,      slot + 40960 + w * 1024);
    } else if (q == 2){
      gload_lds16(bS0 + kbB + 32, slot + 49152 + w * 1024);
      gload_lds16(bS1 + kbB + 32, slot + 57344 + w * 1024);
    } else {
      gload_lds16(aS0 + kbA + 32, slot + 16384 + w * 1024);
      gload_lds16(aS1 + kbA + 32, slot + 24576 + w * 1024);
    }
  };

  // frag register sets (phase pipeline)
  bf16x8 rA0[4], rB0[4];   // used P0: A.k0 m0-3, B.k0
  bf16x8 rA1[4];           // used P1: A.k0 m4-7
  bf16x8 rA2[4], rB2[4];   // used P2: A.k1 m0-3, B.k1
  bf16x8 rA3[4];           // used P3: A.k1 m4-7

  auto READ_P0 = [&](const char* sb){           // 8 reads
#pragma unroll
    for (int m = 0; m < 4; m++) rA0[m] = *(const bf16x8*)(sb + wm * 8192 + m * 1024 + rps);
#pragma unroll
    for (int n = 0; n < 4; n++) rB0[n] = *(const bf16x8*)(sb + 32768 + wn * 4096 + n * 1024 + rps);
  };
  auto READ_P1 = [&](const char* sb){           // 4 reads
#pragma unroll
    for (int m = 0; m < 4; m++) rA1[m] = *(const bf16x8*)(sb + wm * 8192 + (m + 4) * 1024 + rps);
  };
  auto READ_P2 = [&](const char* sb){           // 8 reads
#pragma unroll
    for (int m = 0; m < 4; m++) rA2[m] = *(const bf16x8*)(sb + 16384 + wm * 8192 + m * 1024 + rps);
#pragma unroll
    for (int n = 0; n < 4; n++) rB2[n] = *(const bf16x8*)(sb + 49152 + wn * 4096 + n * 1024 + rps);
  };
  auto READ_P3 = [&](const char* sb){           // 4 reads
#pragma unroll
    for (int m = 0; m < 4; m++) rA3[m] = *(const bf16x8*)(sb + 16384 + wm * 8192 + (m + 4) * 1024 + rps);
  };

  // prologue: stage full tile 0; certify q0,q1(0) for all waves; issue R0
  STAGE_Q(0, 0); STAGE_Q(0, 1); STAGE_Q(0, 2); STAGE_Q(0, 3);
  VM(4);                                        // own q0,q1(0) landed
  BAR();                                        // => ALL waves' q0,q1(0) landed
  READ_P0(ldsb);

#pragma unroll 1
  for (int t = 0; t < NK; t++){
    const char* sb = ldsb + (size_t)(t & 1) * 65536;
    const char* nb = ldsb + (size_t)((t + 1) & 1) * 65536;
    const bool pre = (t + 1 < NK);

    // ---- P0: MFMA R0 ----
    READ_P1(sb);                                // A.k0 certified (G1@P2(t-1) / prologue)
    if (pre) STAGE_Q(t + 1, 0);
    if (pre) { VM(2); } else { VM(0); }         // G2: q2,q3(t) landed (pre-BAR!)
    LGKM(4);                                    // R0 retired, R1 in flight
    __builtin_amdgcn_s_setprio(1);
#pragma unroll
    for (int m = 0; m < 4; m++)
#pragma unroll
      for (int n = 0; n < 4; n++)
        acc[m][n] = __builtin_amdgcn_mfma_f32_16x16x32_bf16(rA0[m], rB0[n], acc[m][n], 0, 0, 0);
    __builtin_amdgcn_s_setprio(0);
    BAR();                                      // => ALL waves' q2,q3(t) landed

    // ---- P1: MFMA R1 ----
    READ_P2(sb);                                // A.k1/B.k1 certified by G2
    if (pre) STAGE_Q(t + 1, 1);
    LGKM(8);                                    // R1 retired, R2 in flight
    __builtin_amdgcn_s_setprio(1);
#pragma unroll
    for (int m = 0; m < 4; m++)
#pragma unroll
      for (int n = 0; n < 4; n++)
        acc[m + 4][n] = __builtin_amdgcn_mfma_f32_16x16x32_bf16(rA1[m], rB0[n], acc[m + 4][n], 0, 0, 0);
    __builtin_amdgcn_s_setprio(0);
    BAR();

    // ---- P2: MFMA R2 ----
    READ_P3(sb);                                // A.k1 certified by G2
    if (pre) STAGE_Q(t + 1, 2);
    if (pre) { VM(2); }                         // G1: q0,q1(t+1) landed (pre-BAR!)
    LGKM(4);                                    // R2 retired, R3 in flight
    __builtin_amdgcn_s_setprio(1);
#pragma unroll
    for (int m = 0; m < 4; m++)
#pragma unroll
      for (int n = 0; n < 4; n++)
        acc[m][n] = __builtin_amdgcn_mfma_f32_16x16x32_bf16(rA2[m], rB2[n], acc[m][n], 0, 0, 0);
    __builtin_amdgcn_s_setprio(0);
    BAR();                                      // => ALL waves' q0,q1(t+1) landed

    // ---- P3: MFMA R3 ----
    if (pre){
      READ_P0(nb);                              // certified by G1
      STAGE_Q(t + 1, 3);
      LGKM(8);                                  // R3 retired, R0' in flight
    } else {
      LGKM0();
    }
    __builtin_amdgcn_s_setprio(1);
#pragma unroll
    for (int m = 0; m < 4; m++)
#pragma unroll
      for (int n = 0; n < 4; n++)
        acc[m + 4][n] = __builtin_amdgcn_mfma_f32_16x16x32_bf16(rA3[m], rB2[n], acc[m + 4][n], 0, 0, 0);
    __builtin_amdgcn_s_setprio(0);
    BAR();
  }

#pragma unroll
  for (int m = 0; m < 8; m++)
#pragma unroll
    for (int n = 0; n < 4; n++){
      const int col  = bn * 256 + wn * 64 + n * 16 + l15;
      const int row0 = bm * 256 + wm * 128 + m * 16 + lg * 4;
      if (EPI == 0){
#pragma unroll
        for (int q = 0; q < 4; q++){
          unsigned short hi, lo; split2(acc[m][n][q], hi, lo);
          const size_t base = (size_t)(row0 + q) * 2048;
          outp[base + col] = hi;
          outp[base + 1024 + col] = lo;
        }
      } else {
        const float bgv = bias[col];
        ushort4 h4;
        h4.x = bf16_rne(acc[m][n][0] + bgv); h4.y = bf16_rne(acc[m][n][1] + bgv);
        h4.z = bf16_rne(acc[m][n][2] + bgv); h4.w = bf16_rne(acc[m][n][3] + bgv);
        *(ushort4*)(outp + (size_t)col * 32768 + row0) = h4;
      }
    }
}

// ============================================================================
// Fused per-frame kernel: scores (K=3072) -> softmax -> PV (out = P @ feats).
// (byte-identical to R5 — verified passing)
// ============================================================================
__global__ __launch_bounds__(256, 1) void k_frame(
    const unsigned short* Y2, const unsigned short* X2,
    const float* __restrict__ v, const unsigned short* __restrict__ FT,
    float* outp)
{
  __shared__ __align__(16) unsigned short lds_u[65536];   // 128 KiB
  char* ldsb = (char*)lds_u;

  const int frame = blockIdx.x;
  const int tid  = threadIdx.x;
  const int w    = tid >> 6;
  const int lane = tid & 63;
  const int wm   = w >> 1, wn = w & 1;
  const int l15  = lane & 15;
  const int lg   = lane >> 4;

  int srow[2], slg[2];
#pragma unroll
  for (int j = 0; j < 2; j++){
    int o = j * 256 + tid;
    int p = o >> 3, s = o & 7;
    int q = s ^ (p & 7);
    srow[j] = 2 * p + (q >> 2);
    slg[j]  = q & 3;
  }
  const unsigned short* yS0 = Y2 + (size_t)(frame * 128 + srow[0]) * 2048 + slg[0] * 8;
  const unsigned short* yS1 = Y2 + (size_t)(frame * 128 + srow[1]) * 2048 + slg[1] * 8;
  const unsigned short* xS0 = X2 + (size_t)(frame * 128 + srow[0]) * 2048 + slg[0] * 8;
  const unsigned short* xS1 = X2 + (size_t)(frame * 128 + srow[1]) * 2048 + slg[1] * 8;

  const int sA  = (((l15 & 1) << 2) | lg) ^ ((l15 >> 1) & 7);
  const int rps = (l15 >> 1) * 128 + sA * 16;

  f32x4 acc[4][4];
  f32x4 zero = {0.f, 0.f, 0.f, 0.f};
#pragma unroll
  for (int m = 0; m < 4; m++)
#pragma unroll
    for (int n = 0; n < 4; n++) acc[m][n] = zero;

  auto STAGE_K = [&](int t, int ks){
    char* slot = ldsb + (size_t)(t & 1) * 32768;
    const int kY = kmap<2>(t * 64) + ks * 32;
    const int kX = kmap<1>(t * 64) + ks * 32;
    gload_lds16(yS0 + kY, slot + ks * 8192 +        tid * 16);
    gload_lds16(yS1 + kY, slot + ks * 8192 + 4096 + tid * 16);
    gload_lds16(xS0 + kX, slot + 16384 + ks * 8192 +        tid * 16);
    gload_lds16(xS1 + kX, slot + 16384 + ks * 8192 + 4096 + tid * 16);
  };

  const int NK = 48;
  STAGE_K(0, 0); STAGE_K(0, 1);

#pragma unroll 1
  for (int t = 0; t < NK; t++){
    const char* sb = ldsb + (size_t)(t & 1) * 32768;
    const bool pre = (t + 1 < NK);
    bf16x8 aF[4], bF[4], aF2[4], bF2[4];

    VM(4);                      // gate1: k0(t) landed (k1(t) allowed)
    BAR();
    if (pre) STAGE_K(t + 1, 0);
#pragma unroll
    for (int m = 0; m < 4; m++) aF[m] = *(const bf16x8*)(sb + wm * 4096 + m * 1024 + rps);
#pragma unroll
    for (int n = 0; n < 4; n++) bF[n] = *(const bf16x8*)(sb + 16384 + wn * 4096 + n * 1024 + rps);
    LGKM0();
    __builtin_amdgcn_s_setprio(1);
#pragma unroll
    for (int m = 0; m < 4; m++)
#pragma unroll
      for (int n = 0; n < 4; n++)
        acc[m][n] = __builtin_amdgcn_mfma_f32_16x16x32_bf16(aF[m], bF[n], acc[m][n], 0, 0, 0);
    __builtin_amdgcn_s_setprio(0);

    if (pre) { VM(4); } else { VM(0); } // gate2: k1(t) landed
    BAR();
    if (pre) STAGE_K(t + 1, 1);
#pragma unroll
    for (int m = 0; m < 4; m++) aF2[m] = *(const bf16x8*)(sb + 8192 + wm * 4096 + m * 1024 + rps);
#pragma unroll
    for (int n = 0; n < 4; n++) bF2[n] = *(const bf16x8*)(sb + 24576 + wn * 4096 + n * 1024 + rps);
    LGKM0();
    __builtin_amdgcn_s_setprio(1);
#pragma unroll
    for (int m = 0; m < 4; m++)
#pragma unroll
      for (int n = 0; n < 4; n++)
        acc[m][n] = __builtin_amdgcn_mfma_f32_16x16x32_bf16(aF2[m], bF2[n], acc[m][n], 0, 0, 0);
    __builtin_amdgcn_s_setprio(0);
  }

  // ---- softmax ----
  BAR();
  float* sf = (float*)ldsb;
#pragma unroll
  for (int m = 0; m < 4; m++)
#pragma unroll
    for (int n = 0; n < 4; n++){
      const int col = wn * 64 + n * 16 + l15;
#pragma unroll
      for (int q = 0; q < 4; q++){
        const int row = wm * 64 + m * 16 + lg * 4 + q;
        sf[row * 128 + ((col + (row & 31) * 4) & 127)] = acc[m][n][q];
      }
    }
  LGKM0(); BAR();
  unsigned short* Pb = (unsigned short*)(ldsb + 65536);
  {
    const float* vr = v + (size_t)frame * 128;
#pragma unroll 1
    for (int i = 0; i < 32; i++){
      const int row = w * 32 + i;
      const float* rp = sf + row * 128;
      const int rot = (row & 31) * 4;
      float a = rp[(lane + rot) & 127]      + vr[lane];
      float b = rp[(lane + 64 + rot) & 127] + vr[lane + 64];
      float mx = fmaxf(a, b);
      for (int o = 32; o; o >>= 1) mx = fmaxf(mx, __shfl_xor(mx, o));
      float ea = __expf(a - mx), eb = __expf(b - mx);
      float s = ea + eb;
      for (int o = 32; o; o >>= 1) s += __shfl_xor(s, o);
      const float inv = 1.0f / s;
      unsigned short* prow = (unsigned short*)((char*)Pb + row * 256);
      const int j0 = lane, j1 = lane + 64;
      *(unsigned short*)((char*)prow + (((j0 >> 3) ^ (row & 15)) * 16) + (j0 & 7) * 2) = bf16_rne(ea * inv);
      *(unsigned short*)((char*)prow + (((j1 >> 3) ^ (row & 15)) * 16) + (j1 & 7) * 2) = bf16_rne(eb * inv);
    }
  }
  LGKM0(); BAR();

  // ---- PV ----
  char* Fb = ldsb + 98304;
  auto STAGE_F = [&](int h){
    char* slot = Fb + (size_t)(h & 1) * 16384;
#pragma unroll
    for (int j = 0; j < 4; j++){
      const int o = j * 256 + tid;
      const int a = o >> 4, c = o & 15;
      gload_lds16(FT + (size_t)(h * 64 + a) * 32768 + frame * 128 + (c ^ (a & 15)) * 8,
                  slot + (size_t)o * 16);
    }
  };
  STAGE_F(0);

#pragma unroll 1
  for (int h = 0; h < 16; h++){
    VM(0);
    BAR();
    if (h + 1 < 16) STAGE_F(h + 1);
    const char* fs = Fb + (size_t)(h & 1) * 16384;
    bf16x8 pF[4][4], fF[4][2];
#pragma unroll
    for (int ks = 0; ks < 4; ks++){
#pragma unroll
      for (int m = 0; m < 4; m++){
        const int row = wm * 64 + m * 16 + l15;
        pF[ks][m] = *(const bf16x8*)((char*)Pb + row * 256 + (((ks * 4 + lg) ^ (row & 15)) * 16));
      }
#pragma unroll
      for (int n = 0; n < 2; n++){
        const int al = wn * 32 + n * 16 + l15;
        fF[ks][n] = *(const bf16x8*)(fs + al * 256 + (((ks * 4 + lg) ^ (al & 15)) * 16));
      }
    }
    LGKM0();
    f32x4 accP[4][2];
#pragma unroll
    for (int m = 0; m < 4; m++)
#pragma unroll
      for (int n = 0; n < 2; n++) accP[m][n] = zero;
    __builtin_amdgcn_s_setprio(1);
#pragma unroll
    for (int ks = 0; ks < 4; ks++)
#pragma unroll
      for (int m = 0; m < 4; m++)
#pragma unroll
        for (int n = 0; n < 2; n++)
          accP[m][n] = __builtin_amdgcn_mfma_f32_16x16x32_bf16(pF[ks][m], fF[ks][n], accP[m][n], 0, 0, 0);
    __builtin_amdgcn_s_setprio(0);
#pragma unroll
    for (int m = 0; m < 4; m++)
#pragma unroll
      for (int n = 0; n < 2; n++){
        const int f = h * 64 + wn * 32 + n * 16 + l15;
        const int r0 = wm * 64 + m * 16 + lg * 4;
#pragma unroll
        for (int q = 0; q < 4; q++)
          outp[((size_t)frame * 128 + r0 + q) * 1024 + f] = accP[m][n][q];
      }
  }
}

// ============================================================================
// m97-style core for the small M=N=1024 GEMM (mt).
// ============================================================================
template<int MAPA, int MAPB>
__device__ __forceinline__ void gemm_core(const unsigned short* __restrict__ A, int lda,
                                          const unsigned short* __restrict__ B, int ldb,
                                          int Kv,
                                          unsigned short* lsA, unsigned short* lsB,
                                          f32x4 acc[4][4])
{
  const int tid  = threadIdx.x;
  const int lane = tid & 63;
  const int w    = tid >> 6;
  const int wr   = (w >> 1) * 64;
  const int wc   = (w & 1) * 64;
  const int l15  = lane & 15;
  const int lg   = lane >> 4;

  f32x4 zero = {0.f, 0.f, 0.f, 0.f};
#pragma unroll
  for (int m = 0; m < 4; m++)
#pragma unroll
    for (int n = 0; n < 4; n++)
      acc[m][n] = zero;

  const int srow = tid >> 3;
  const int skk  = (tid & 7) << 3;

  for (int kt = 0; kt < Kv; kt += 64){
    const int ka = kmap<MAPA>(kt) + skk;
    const int kb = kmap<MAPB>(kt) + skk;
    __syncthreads();
#pragma unroll
    for (int i = 0; i < 4; i++){
      const int row = i * 32 + srow;
      gload_lds16(A + (size_t)row * lda + ka, lsA + i * 2048 + w * 512);
      gload_lds16(B + (size_t)row * ldb + kb, lsB + i * 2048 + w * 512);
    }
    __syncthreads();
#pragma unroll
    for (int s2 = 0; s2 < 2; s2++){
      bf16x8 af[4], bfr[4];
#pragma unroll
      for (int m = 0; m < 4; m++)
        af[m] = *(const bf16x8*)(lsA + (wr + m * 16 + l15) * 64 + s2 * 32 + lg * 8);
#pragma unroll
      for (int n = 0; n < 4; n++)
        bfr[n] = *(const bf16x8*)(lsB + (wc + n * 16 + l15) * 64 + s2 * 32 + lg * 8);
#pragma unroll
      for (int m = 0; m < 4; m++)
#pragma unroll
        for (int n = 0; n < 4; n++)
          acc[m][n] = __builtin_amdgcn_mfma_f32_16x16x32_bf16(af[m], bfr[n], acc[m][n], 0, 0, 0);
    }
  }
}

// ---------- small prep kernels ----------
__global__ __launch_bounds__(256) void k_split(const float* __restrict__ src,
                                               unsigned short* __restrict__ dst){
  const int row = blockIdx.x;
  const int c = threadIdx.x * 4;
  float4 val = *(const float4*)(src + (size_t)row * 1024 + c);
  ushort4 h, l;
  split2(val.x, h.x, l.x); split2(val.y, h.y, l.y);
  split2(val.z, h.z, l.z); split2(val.w, h.w, l.w);
  *(ushort4*)(dst + (size_t)row * 2048 + c) = h;
  *(ushort4*)(dst + (size_t)row * 2048 + 1024 + c) = l;
}

__global__ __launch_bounds__(256) void k_splitT(const float* __restrict__ src,
                                                unsigned short* __restrict__ dstT){
  const int row = blockIdx.x;
  const int c0 = threadIdx.x * 4;
  float4 val = *(const float4*)(src + (size_t)row * 1024 + c0);
  float vv[4] = {val.x, val.y, val.z, val.w};
#pragma unroll
  for (int i = 0; i < 4; i++){
    unsigned short h, l; split2(vv[i], h, l);
    dstT[(size_t)(c0 + i) * 2048 + row] = h;
    dstT[(size_t)(c0 + i) * 2048 + 1024 + row] = l;
  }
}

__global__ __launch_bounds__(256) void k_wv(const float* __restrict__ Wb,
                                            const float* __restrict__ ba,
                                            float* __restrict__ wv){
  const int row = blockIdx.x * 4 + (threadIdx.x >> 6);
  const int lane = threadIdx.x & 63;
  float s = 0.f;
#pragma unroll
  for (int j = 0; j < 4; j++){
    const int c = lane * 4 + j * 256;
    float4 wb = *(const float4*)(Wb + (size_t)row * 1024 + c);
    float4 bb = *(const float4*)(ba + c);
    s += wb.x * bb.x + wb.y * bb.y + wb.z * bb.z + wb.w * bb.w;
  }
  for (int o = 32; o; o >>= 1) s += __shfl_xor(s, o);
  if (lane == 0) wv[row] = s;
}

__global__ __launch_bounds__(256) void k_split_x(const float* __restrict__ x,
                                                 unsigned short* __restrict__ x2,
                                                 const float* __restrict__ wv,
                                                 float* __restrict__ v){
  const int w = threadIdx.x >> 6, lane = threadIdx.x & 63;
#pragma unroll
  for (int it = 0; it < 4; it++){
    const int row = blockIdx.x * 4 + w + it * 8192;
    float s = 0.f;
#pragma unroll
    for (int j = 0; j < 4; j++){
      const int c = lane * 4 + j * 256;
      float4 val = *(const float4*)(x + (size_t)row * 1024 + c);
      float4 wvv = *(const float4*)(wv + c);
      ushort4 h, l;
      split2(val.x, h.x, l.x); split2(val.y, h.y, l.y);
      split2(val.z, h.z, l.z); split2(val.w, h.w, l.w);
      *(ushort4*)(x2 + (size_t)row * 2048 + c) = h;
      *(ushort4*)(x2 + (size_t)row * 2048 + 1024 + c) = l;
      s += val.x * wvv.x + val.y * wvv.y + val.z * wvv.z + val.w * wvv.w;
    }
    for (int o = 32; o; o >>= 1) s += __shfl_xor(s, o);
    if (lane == 0) v[row] = s;
  }
}

// M = Wa*Wb^T 3-term split; write M^T split. grid 64.
__global__ __launch_bounds__(256) void k_gemm_mt(const unsigned short* __restrict__ Wa2,
                                                 const unsigned short* __restrict__ Wb2,
                                                 unsigned short* __restrict__ MT2){
  __shared__ __align__(16) unsigned short lsA[8192], lsB[8192];
  const int bm = blockIdx.x >> 3, bn = blockIdx.x & 7;
  f32x4 acc[4][4];
  gemm_core<1, 2>(Wa2 + (size_t)bm * 128 * 2048, 2048,
                  Wb2 + (size_t)bn * 128 * 2048, 2048, 3072, lsA, lsB, acc);
  const int tid = threadIdx.x, lane = tid & 63, w = tid >> 6;
  const int wr = (w >> 1) * 64, wc = (w & 1) * 64, l15 = lane & 15, lg = lane >> 4;
#pragma unroll
  for (int m = 0; m < 4; m++)
#pragma unroll
    for (int n = 0; n < 4; n++){
      const int g  = bn * 128 + wc + n * 16 + l15;
      const int f0 = bm * 128 + wr + m * 16 + lg * 4;
      ushort4 h4, l4;
      split2(acc[m][n][0], h4.x, l4.x); split2(acc[m][n][1], h4.y, l4.y);
      split2(acc[m][n][2], h4.z, l4.z); split2(acc[m][n][3], h4.w, l4.w);
      *(ushort4*)(MT2 + (size_t)g * 2048 + f0) = h4;
      *(ushort4*)(MT2 + (size_t)g * 2048 + 1024 + f0) = l4;
    }
}

// ---------- launcher ----------
extern "C" void kernel_launch(void* const* d_in, const int* in_sizes, int n_in,
                              void* d_out, int out_size, void* d_ws, size_t ws_size,
                              hipStream_t stream) {
  const float* x  = (const float*)d_in[0];
  const float* Wa = (const float*)d_in[2];
  const float* ba = (const float*)d_in[3];
  const float* Wb = (const float*)d_in[4];
  const float* Wg = (const float*)d_in[6];
  const float* bg = (const float*)d_in[7];

  unsigned short* x2  = (unsigned short*)d_ws;            // 32768 x 2048
  unsigned short* Wa2 = x2 + (size_t)32768 * 2048;        // 1024 x 2048
  unsigned short* Wb2 = Wa2 + (size_t)1024 * 2048;        // 1024 x 2048
  unsigned short* WgT = Wb2 + (size_t)1024 * 2048;        // 1024 x 2048
  unsigned short* MT2 = WgT + (size_t)1024 * 2048;        // 1024 x 2048
  unsigned short* FT  = MT2 + (size_t)1024 * 2048;        // 1024 x 32768 (feats^T bf16)
  float* wv = (float*)(FT + (size_t)1024 * 32768);        // 1024
  float* v  = wv + 1024;                                  // 32768
  size_t need = (size_t)((char*)(v + 32768) - (char*)d_ws);
  if (ws_size < need) return;

  unsigned short* y2 = (unsigned short*)d_out;            // y hi/lo in d_out until PV

  k_split   <<<1024, 256, 0, stream>>>(Wa, Wa2);
  k_split   <<<1024, 256, 0, stream>>>(Wb, Wb2);
  k_splitT  <<<1024, 256, 0, stream>>>(Wg, WgT);
  k_wv      <<<256,  256, 0, stream>>>(Wb, ba, wv);
  k_split_x <<<2048, 256, 0, stream>>>(x, x2, wv, v);
  k_gemm_mt <<<64,   256, 0, stream>>>(Wa2, Wb2, MT2);
  k_gemm256<0, 0, 16, 1><<<512, 512, 0, stream>>>(x2, WgT, FT, bg);      // featsT
  k_gemm256<1, 2, 48, 0><<<512, 512, 0, stream>>>(x2, MT2, y2, nullptr); // y = x*M
  k_frame   <<<256,  256, 0, stream>>>(y2, x2, v, FT, (float*)d_out);    // scores+softmax+PV
}

// Round 8
// 530.312 us; speedup vs baseline: 1.0009x; 1.0009x over previous
//
#include <hip/hip_runtime.h>

typedef __attribute__((ext_vector_type(8))) short bf16x8;
typedef __attribute__((ext_vector_type(4))) float f32x4;

// ---------- helpers ----------
__device__ __forceinline__ unsigned short bf16_rne(float x){
  unsigned int u = __float_as_uint(x);
  unsigned int r = (u + 0x7FFFu + ((u >> 16) & 1u)) >> 16;
  return (unsigned short)r;
}
__device__ __forceinline__ float bf16_tof(unsigned short h){
  return __uint_as_float(((unsigned int)h) << 16);
}
__device__ __forceinline__ void split2(float x, unsigned short &hi, unsigned short &lo){
  hi = bf16_rne(x);
  lo = bf16_rne(x - bf16_tof(hi));
}
__device__ __forceinline__ void gload_lds16(const void* g, void* l){
  __builtin_amdgcn_global_load_lds((const __attribute__((address_space(1))) void*)g,
                                   (__attribute__((address_space(3))) void*)l, 16, 0, 0);
}
#define VM(N)    asm volatile("s_waitcnt vmcnt(" #N ")" ::: "memory")
#define LGKM0()  do { asm volatile("s_waitcnt lgkmcnt(0)" ::: "memory"); \
                      __builtin_amdgcn_sched_barrier(0); } while(0)
#define BAR()    do { __builtin_amdgcn_s_barrier(); \
                      __builtin_amdgcn_sched_barrier(0); } while(0)

// K-index remap for the 3-term split expressed as a K=3072 concat GEMM.
// MAP 0: identity. MAP 1: blocks [hi|lo|hi]. MAP 2: blocks [hi|hi|lo].
template<int MAP>
__device__ __forceinline__ int kmap(int k){
  if (MAP == 1) return (k < 2048) ? k : (k - 2048);
  if (MAP == 2) return (k < 1024) ? k : (k - 1024);
  return k;
}

// ============================================================================
// 256x256 GEMM, BK=64, 512 threads (8 waves 2x4) — m201-topology phases.
// LDS = ring of 4 units x 32 KiB; unit u = (tile u>>1, ksub u&1) =
// [A-half 16K | B-half 16K], staged 3 units ahead, 2 gloads/wave/phase.
// Phase = { READ frags (4-8 ds_read) ; STAGE(2) ; [VM gate] ; bar1 ;
//           lgkm(0) ; setprio(1) 16xMFMA setprio(0) ; bar2 }  (x4 per tile)
// Reads overlap bar1-wait + (via <=1-phase wave skew) other waves' MFMA.
//
// Gload FIFO per wave (4 loads/unit): prologue units 0,1,2; then
// P0(t): u+3 part0, P1(t): u+3 part1, P2(t): u+4 part0, P3(t): u+4 part1
// (u = 2t). Gates (pre-bar1, after the phase's STAGE):
//   P1(t): out = {u+1,u+2,u+3} = 12 -> VM(8) retires u+1
//          (certifies unit u+1 for reads at P2/P3, which follow bar1+bar2)
//   P3(t): out = {u+2,u+3,u+4} = 12 -> VM(8) retires u+2
//          (certifies unit u+2 for reads at P0/P1 of tile t+1)
// Tail: t=NK-2: P3 out = {u+2,u+3} = 8 -> VM(4); t=NK-1: P1 VM(0), P3 none.
// WAR: unit u-1's last read retires at lgkm0(P3(t-1)) pre-bar2; its slot is
// overwritten by STAGE(u+3)@P0(t) — >=1 barrier later. Unit u's slot is
// overwritten by STAGE(u+4)@P2(t), >=1 barrier after lgkm0(P1(t)). SAFE.
// XOR-swizzled LDS regions (R2-verified 0 bank conflicts; same addresses).
// EPI 0: split hi/lo write (y). EPI 1: bf16(acc+bias[col])^T write (featsT).
// ============================================================================
template<int MAPA, int MAPB, int NK, int EPI>
__global__ __launch_bounds__(512, 2) void k_gemm256(
    const unsigned short* __restrict__ A, const unsigned short* __restrict__ B,
    unsigned short* __restrict__ outp, const float* __restrict__ bias)
{
  __shared__ __align__(16) unsigned short lds_u[65536];   // 128 KiB
  char* ldsb = (char*)lds_u;

  int bid = blockIdx.x;                 // XCD-aware swizzle (grid 512 % 8 == 0)
  bid = (bid & 7) * 64 + (bid >> 3);
  const int bm = bid >> 2, bn = bid & 3;

  const int tid  = threadIdx.x;
  const int w    = tid >> 6;
  const int lane = tid & 63;
  const int wm   = w >> 2;              // 0..1
  const int wn   = w & 3;               // 0..3
  const int l15  = lane & 15;
  const int lg   = lane >> 4;

  // staging source map (inverse swizzle), 2 chunks per 16K region
  int srow[2], slg[2];
#pragma unroll
  for (int j = 0; j < 2; j++){
    int o16 = j * 512 + tid;
    int p = o16 >> 3, s = o16 & 7;
    int q = s ^ (p & 7);
    srow[j] = 2 * p + (q >> 2);
    slg[j]  = q & 3;
  }
  const unsigned short* aS0 = A + (size_t)(bm * 256 + srow[0]) * 2048 + slg[0] * 8;
  const unsigned short* aS1 = A + (size_t)(bm * 256 + srow[1]) * 2048 + slg[1] * 8;
  const unsigned short* bS0 = B + (size_t)(bn * 256 + srow[0]) * 2048 + slg[0] * 8;
  const unsigned short* bS1 = B + (size_t)(bn * 256 + srow[1]) * 2048 + slg[1] * 8;

  const int sA   = (((l15 & 1) << 2) | lg) ^ ((l15 >> 1) & 7);
  const int rps  = (l15 >> 1) * 128 + sA * 16;

  f32x4 acc[8][4];
  f32x4 zero = {0.f, 0.f, 0.f, 0.f};
#pragma unroll
  for (int m = 0; m < 8; m++)
#pragma unroll
    for (int n = 0; n < 4; n++) acc[m][n] = zero;

  // unit u: tile u>>1, ksub u&1; slot (u&3)*32K; [A 16K | B 16K]
  auto STAGE_U = [&](int u, int part){
    char* slot = ldsb + (size_t)(u & 3) * 32768;
    const int t = u >> 1, h = u & 1;
    if (part == 0){
      const int kA = kmap<MAPA>(t * 64) + h * 32;
      gload_lds16(aS0 + kA, slot +        w * 1024);
      gload_lds16(aS1 + kA, slot + 8192 + w * 1024);
    } else {
      const int kB = kmap<MAPB>(t * 64) + h * 32;
      gload_lds16(bS0 + kB, slot + 16384 +        w * 1024);
      gload_lds16(bS1 + kB, slot + 16384 + 8192 + w * 1024);
    }
  };

  bf16x8 rA[4], rB[4], rAx[4];

  // prologue: stage units 0,1,2 (12 loads); certify unit 0 for all waves
  STAGE_U(0, 0); STAGE_U(0, 1);
  STAGE_U(1, 0); STAGE_U(1, 1);
  STAGE_U(2, 0); STAGE_U(2, 1);
  VM(8);                                // unit 0 landed (1,2 in flight)
  BAR();

#pragma unroll 1
  for (int t = 0; t < NK; t++){
    const char* s0 = ldsb + (size_t)((2 * t) & 3) * 32768;
    const char* s1 = ldsb + (size_t)((2 * t + 1) & 3) * 32768;
    const bool p1 = (t + 1 < NK);       // stage unit 2t+3
    const bool p2 = (t + 2 < NK);       // stage unit 2t+4

    // ---- P0: A.k0 m0-3 x B.k0 ----
#pragma unroll
    for (int m = 0; m < 4; m++) rA[m] = *(const bf16x8*)(s0 + wm * 8192 + m * 1024 + rps);
#pragma unroll
    for (int n = 0; n < 4; n++) rB[n] = *(const bf16x8*)(s0 + 16384 + wn * 4096 + n * 1024 + rps);
    if (p1) STAGE_U(2 * t + 3, 0);
    BAR();
    LGKM0();
    __builtin_amdgcn_s_setprio(1);
#pragma unroll
    for (int m = 0; m < 4; m++)
#pragma unroll
      for (int n = 0; n < 4; n++)
        acc[m][n] = __builtin_amdgcn_mfma_f32_16x16x32_bf16(rA[m], rB[n], acc[m][n], 0, 0, 0);
    __builtin_amdgcn_s_setprio(0);
    BAR();

    // ---- P1: A.k0 m4-7 x B.k0 ----
#pragma unroll
    for (int m = 0; m < 4; m++) rAx[m] = *(const bf16x8*)(s0 + wm * 8192 + (m + 4) * 1024 + rps);
    if (p1) STAGE_U(2 * t + 3, 1);
    if (p1) { VM(8); } else { VM(0); }  // retire unit 2t+1 -> readable at P2/P3
    BAR();
    LGKM0();
    __builtin_amdgcn_s_setprio(1);
#pragma unroll
    for (int m = 0; m < 4; m++)
#pragma unroll
      for (int n = 0; n < 4; n++)
        acc[m + 4][n] = __builtin_amdgcn_mfma_f32_16x16x32_bf16(rAx[m], rB[n], acc[m + 4][n], 0, 0, 0);
    __builtin_amdgcn_s_setprio(0);
    BAR();

    // ---- P2: A.k1 m0-3 x B.k1 ----
#pragma unroll
    for (int m = 0; m < 4; m++) rA[m] = *(const bf16x8*)(s1 + wm * 8192 + m * 1024 + rps);
#pragma unroll
    for (int n = 0; n < 4; n++) rB[n] = *(const bf16x8*)(s1 + 16384 + wn * 4096 + n * 1024 + rps);
    if (p2) STAGE_U(2 * t + 4, 0);
    BAR();
    LGKM0();
    __builtin_amdgcn_s_setprio(1);
#pragma unroll
    for (int m = 0; m < 4; m++)
#pragma unroll
      for (int n = 0; n < 4; n++)
        acc[m][n] = __builtin_amdgcn_mfma_f32_16x16x32_bf16(rA[m], rB[n], acc[m][n], 0, 0, 0);
    __builtin_amdgcn_s_setprio(0);
    BAR();

    // ---- P3: A.k1 m4-7 x B.k1 ----
#pragma unroll
    for (int m = 0; m < 4; m++) rAx[m] = *(const bf16x8*)(s1 + wm * 8192 + (m + 4) * 1024 + rps);
    if (p2) STAGE_U(2 * t + 4, 1);
    if (p2)      { VM(8); }             // retire unit 2t+2 -> readable next tile
    else if (p1) { VM(4); }             // tail t=NK-2: out={u+2,u+3}=8 -> VM(4)
    BAR();
    LGKM0();
    __builtin_amdgcn_s_setprio(1);
#pragma unroll
    for (int m = 0; m < 4; m++)
#pragma unroll
      for (int n = 0; n < 4; n++)
        acc[m + 4][n] = __builtin_amdgcn_mfma_f32_16x16x32_bf16(rAx[m], rB[n], acc[m + 4][n], 0, 0, 0);
    __builtin_amdgcn_s_setprio(0);
    BAR();
  }

#pragma unroll
  for (int m = 0; m < 8; m++)
#pragma unroll
    for (int n = 0; n < 4; n++){
      const int col  = bn * 256 + wn * 64 + n * 16 + l15;
      const int row0 = bm * 256 + wm * 128 + m * 16 + lg * 4;
      if (EPI == 0){
#pragma unroll
        for (int q = 0; q < 4; q++){
          unsigned short hi, lo; split2(acc[m][n][q], hi, lo);
          const size_t base = (size_t)(row0 + q) * 2048;
          outp[base + col] = hi;
          outp[base + 1024 + col] = lo;
        }
      } else {
        const float bgv = bias[col];
        ushort4 h4;
        h4.x = bf16_rne(acc[m][n][0] + bgv); h4.y = bf16_rne(acc[m][n][1] + bgv);
        h4.z = bf16_rne(acc[m][n][2] + bgv); h4.w = bf16_rne(acc[m][n][3] + bgv);
        *(ushort4*)(outp + (size_t)col * 32768 + row0) = h4;
      }
    }
}

// ============================================================================
// Fused per-frame kernel: scores (K=3072) -> softmax -> PV (out = P @ feats).
// (byte-identical to R5/R7 — verified passing)
// ============================================================================
__global__ __launch_bounds__(256, 1) void k_frame(
    const unsigned short* Y2, const unsigned short* X2,
    const float* __restrict__ v, const unsigned short* __restrict__ FT,
    float* outp)
{
  __shared__ __align__(16) unsigned short lds_u[65536];   // 128 KiB
  char* ldsb = (char*)lds_u;

  const int frame = blockIdx.x;
  const int tid  = threadIdx.x;
  const int w    = tid >> 6;
  const int lane = tid & 63;
  const int wm   = w >> 1, wn = w & 1;
  const int l15  = lane & 15;
  const int lg   = lane >> 4;

  int srow[2], slg[2];
#pragma unroll
  for (int j = 0; j < 2; j++){
    int o = j * 256 + tid;
    int p = o >> 3, s = o & 7;
    int q = s ^ (p & 7);
    srow[j] = 2 * p + (q >> 2);
    slg[j]  = q & 3;
  }
  const unsigned short* yS0 = Y2 + (size_t)(frame * 128 + srow[0]) * 2048 + slg[0] * 8;
  const unsigned short* yS1 = Y2 + (size_t)(frame * 128 + srow[1]) * 2048 + slg[1] * 8;
  const unsigned short* xS0 = X2 + (size_t)(frame * 128 + srow[0]) * 2048 + slg[0] * 8;
  const unsigned short* xS1 = X2 + (size_t)(frame * 128 + srow[1]) * 2048 + slg[1] * 8;

  const int sA  = (((l15 & 1) << 2) | lg) ^ ((l15 >> 1) & 7);
  const int rps = (l15 >> 1) * 128 + sA * 16;

  f32x4 acc[4][4];
  f32x4 zero = {0.f, 0.f, 0.f, 0.f};
#pragma unroll
  for (int m = 0; m < 4; m++)
#pragma unroll
    for (int n = 0; n < 4; n++) acc[m][n] = zero;

  auto STAGE_K = [&](int t, int ks){
    char* slot = ldsb + (size_t)(t & 1) * 32768;
    const int kY = kmap<2>(t * 64) + ks * 32;
    const int kX = kmap<1>(t * 64) + ks * 32;
    gload_lds16(yS0 + kY, slot + ks * 8192 +        tid * 16);
    gload_lds16(yS1 + kY, slot + ks * 8192 + 4096 + tid * 16);
    gload_lds16(xS0 + kX, slot + 16384 + ks * 8192 +        tid * 16);
    gload_lds16(xS1 + kX, slot + 16384 + ks * 8192 + 4096 + tid * 16);
  };

  const int NK = 48;
  STAGE_K(0, 0); STAGE_K(0, 1);

#pragma unroll 1
  for (int t = 0; t < NK; t++){
    const char* sb = ldsb + (size_t)(t & 1) * 32768;
    const bool pre = (t + 1 < NK);
    bf16x8 aF[4], bF[4], aF2[4], bF2[4];

    VM(4);                      // gate1: k0(t) landed (k1(t) allowed)
    BAR();
    if (pre) STAGE_K(t + 1, 0);
#pragma unroll
    for (int m = 0; m < 4; m++) aF[m] = *(const bf16x8*)(sb + wm * 4096 + m * 1024 + rps);
#pragma unroll
    for (int n = 0; n < 4; n++) bF[n] = *(const bf16x8*)(sb + 16384 + wn * 4096 + n * 1024 + rps);
    LGKM0();
    __builtin_amdgcn_s_setprio(1);
#pragma unroll
    for (int m = 0; m < 4; m++)
#pragma unroll
      for (int n = 0; n < 4; n++)
        acc[m][n] = __builtin_amdgcn_mfma_f32_16x16x32_bf16(aF[m], bF[n], acc[m][n], 0, 0, 0);
    __builtin_amdgcn_s_setprio(0);

    if (pre) { VM(4); } else { VM(0); } // gate2: k1(t) landed
    BAR();
    if (pre) STAGE_K(t + 1, 1);
#pragma unroll
    for (int m = 0; m < 4; m++) aF2[m] = *(const bf16x8*)(sb + 8192 + wm * 4096 + m * 1024 + rps);
#pragma unroll
    for (int n = 0; n < 4; n++) bF2[n] = *(const bf16x8*)(sb + 24576 + wn * 4096 + n * 1024 + rps);
    LGKM0();
    __builtin_amdgcn_s_setprio(1);
#pragma unroll
    for (int m = 0; m < 4; m++)
#pragma unroll
      for (int n = 0; n < 4; n++)
        acc[m][n] = __builtin_amdgcn_mfma_f32_16x16x32_bf16(aF2[m], bF2[n], acc[m][n], 0, 0, 0);
    __builtin_amdgcn_s_setprio(0);
  }

  // ---- softmax ----
  BAR();
  float* sf = (float*)ldsb;
#pragma unroll
  for (int m = 0; m < 4; m++)
#pragma unroll
    for (int n = 0; n < 4; n++){
      const int col = wn * 64 + n * 16 + l15;
#pragma unroll
      for (int q = 0; q < 4; q++){
        const int row = wm * 64 + m * 16 + lg * 4 + q;
        sf[row * 128 + ((col + (row & 31) * 4) & 127)] = acc[m][n][q];
      }
    }
  LGKM0(); BAR();
  unsigned short* Pb = (unsigned short*)(ldsb + 65536);
  {
    const float* vr = v + (size_t)frame * 128;
#pragma unroll 1
    for (int i = 0; i < 32; i++){
      const int row = w * 32 + i;
      const float* rp = sf + row * 128;
      const int rot = (row & 31) * 4;
      float a = rp[(lane + rot) & 127]      + vr[lane];
      float b = rp[(lane + 64 + rot) & 127] + vr[lane + 64];
      float mx = fmaxf(a, b);
      for (int o = 32; o; o >>= 1) mx = fmaxf(mx, __shfl_xor(mx, o));
      float ea = __expf(a - mx), eb = __expf(b - mx);
      float s = ea + eb;
      for (int o = 32; o; o >>= 1) s += __shfl_xor(s, o);
      const float inv = 1.0f / s;
      unsigned short* prow = (unsigned short*)((char*)Pb + row * 256);
      const int j0 = lane, j1 = lane + 64;
      *(unsigned short*)((char*)prow + (((j0 >> 3) ^ (row & 15)) * 16) + (j0 & 7) * 2) = bf16_rne(ea * inv);
      *(unsigned short*)((char*)prow + (((j1 >> 3) ^ (row & 15)) * 16) + (j1 & 7) * 2) = bf16_rne(eb * inv);
    }
  }
  LGKM0(); BAR();

  // ---- PV ----
  char* Fb = ldsb + 98304;
  auto STAGE_F = [&](int h){
    char* slot = Fb + (size_t)(h & 1) * 16384;
#pragma unroll
    for (int j = 0; j < 4; j++){
      const int o = j * 256 + tid;
      const int a = o >> 4, c = o & 15;
      gload_lds16(FT + (size_t)(h * 64 + a) * 32768 + frame * 128 + (c ^ (a & 15)) * 8,
                  slot + (size_t)o * 16);
    }
  };
  STAGE_F(0);

#pragma unroll 1
  for (int h = 0; h < 16; h++){
    VM(0);
    BAR();
    if (h + 1 < 16) STAGE_F(h + 1);
    const char* fs = Fb + (size_t)(h & 1) * 16384;
    bf16x8 pF[4][4], fF[4][2];
#pragma unroll
    for (int ks = 0; ks < 4; ks++){
#pragma unroll
      for (int m = 0; m < 4; m++){
        const int row = wm * 64 + m * 16 + l15;
        pF[ks][m] = *(const bf16x8*)((char*)Pb + row * 256 + (((ks * 4 + lg) ^ (row & 15)) * 16));
      }
#pragma unroll
      for (int n = 0; n < 2; n++){
        const int al = wn * 32 + n * 16 + l15;
        fF[ks][n] = *(const bf16x8*)(fs + al * 256 + (((ks * 4 + lg) ^ (al & 15)) * 16));
      }
    }
    LGKM0();
    f32x4 accP[4][2];
#pragma unroll
    for (int m = 0; m < 4; m++)
#pragma unroll
      for (int n = 0; n < 2; n++) accP[m][n] = zero;
    __builtin_amdgcn_s_setprio(1);
#pragma unroll
    for (int ks = 0; ks < 4; ks++)
#pragma unroll
      for (int m = 0; m < 4; m++)
#pragma unroll
        for (int n = 0; n < 2; n++)
          accP[m][n] = __builtin_amdgcn_mfma_f32_16x16x32_bf16(pF[ks][m], fF[ks][n], accP[m][n], 0, 0, 0);
    __builtin_amdgcn_s_setprio(0);
#pragma unroll
    for (int m = 0; m < 4; m++)
#pragma unroll
      for (int n = 0; n < 2; n++){
        const int f = h * 64 + wn * 32 + n * 16 + l15;
        const int r0 = wm * 64 + m * 16 + lg * 4;
#pragma unroll
        for (int q = 0; q < 4; q++)
          outp[((size_t)frame * 128 + r0 + q) * 1024 + f] = accP[m][n][q];
      }
  }
}

// ============================================================================
// m97-style core for the small M=N=1024 GEMM (mt).
// ============================================================================
template<int MAPA, int MAPB>
__device__ __forceinline__ void gemm_core(const unsigned short* __restrict__ A, int lda,
                                          const unsigned short* __restrict__ B, int ldb,
                                          int Kv,
                                          unsigned short* lsA, unsigned short* lsB,
                                          f32x4 acc[4][4])
{
  const int tid  = threadIdx.x;
  const int lane = tid & 63;
  const int w    = tid >> 6;
  const int wr   = (w >> 1) * 64;
  const int wc   = (w & 1) * 64;
  const int l15  = lane & 15;
  const int lg   = lane >> 4;

  f32x4 zero = {0.f, 0.f, 0.f, 0.f};
#pragma unroll
  for (int m = 0; m < 4; m++)
#pragma unroll
    for (int n = 0; n < 4; n++)
      acc[m][n] = zero;

  const int srow = tid >> 3;
  const int skk  = (tid & 7) << 3;

  for (int kt = 0; kt < Kv; kt += 64){
    const int ka = kmap<MAPA>(kt) + skk;
    const int kb = kmap<MAPB>(kt) + skk;
    __syncthreads();
#pragma unroll
    for (int i = 0; i < 4; i++){
      const int row = i * 32 + srow;
      gload_lds16(A + (size_t)row * lda + ka, lsA + i * 2048 + w * 512);
      gload_lds16(B + (size_t)row * ldb + kb, lsB + i * 2048 + w * 512);
    }
    __syncthreads();
#pragma unroll
    for (int s2 = 0; s2 < 2; s2++){
      bf16x8 af[4], bfr[4];
#pragma unroll
      for (int m = 0; m < 4; m++)
        af[m] = *(const bf16x8*)(lsA + (wr + m * 16 + l15) * 64 + s2 * 32 + lg * 8);
#pragma unroll
      for (int n = 0; n < 4; n++)
        bfr[n] = *(const bf16x8*)(lsB + (wc + n * 16 + l15) * 64 + s2 * 32 + lg * 8);
#pragma unroll
      for (int m = 0; m < 4; m++)
#pragma unroll
        for (int n = 0; n < 4; n++)
          acc[m][n] = __builtin_amdgcn_mfma_f32_16x16x32_bf16(af[m], bfr[n], acc[m][n], 0, 0, 0);
    }
  }
}

// ---------- small prep kernels ----------
__global__ __launch_bounds__(256) void k_split(const float* __restrict__ src,
                                               unsigned short* __restrict__ dst){
  const int row = blockIdx.x;
  const int c = threadIdx.x * 4;
  float4 val = *(const float4*)(src + (size_t)row * 1024 + c);
  ushort4 h, l;
  split2(val.x, h.x, l.x); split2(val.y, h.y, l.y);
  split2(val.z, h.z, l.z); split2(val.w, h.w, l.w);
  *(ushort4*)(dst + (size_t)row * 2048 + c) = h;
  *(ushort4*)(dst + (size_t)row * 2048 + 1024 + c) = l;
}

__global__ __launch_bounds__(256) void k_splitT(const float* __restrict__ src,
                                                unsigned short* __restrict__ dstT){
  const int row = blockIdx.x;
  const int c0 = threadIdx.x * 4;
  float4 val = *(const float4*)(src + (size_t)row * 1024 + c0);
  float vv[4] = {val.x, val.y, val.z, val.w};
#pragma unroll
  for (int i = 0; i < 4; i++){
    unsigned short h, l; split2(vv[i], h, l);
    dstT[(size_t)(c0 + i) * 2048 + row] = h;
    dstT[(size_t)(c0 + i) * 2048 + 1024 + row] = l;
  }
}

__global__ __launch_bounds__(256) void k_wv(const float* __restrict__ Wb,
                                            const float* __restrict__ ba,
                                            float* __restrict__ wv){
  const int row = blockIdx.x * 4 + (threadIdx.x >> 6);
  const int lane = threadIdx.x & 63;
  float s = 0.f;
#pragma unroll
  for (int j = 0; j < 4; j++){
    const int c = lane * 4 + j * 256;
    float4 wb = *(const float4*)(Wb + (size_t)row * 1024 + c);
    float4 bb = *(const float4*)(ba + c);
    s += wb.x * bb.x + wb.y * bb.y + wb.z * bb.z + wb.w * bb.w;
  }
  for (int o = 32; o; o >>= 1) s += __shfl_xor(s, o);
  if (lane == 0) wv[row] = s;
}

__global__ __launch_bounds__(256) void k_split_x(const float* __restrict__ x,
                                                 unsigned short* __restrict__ x2,
                                                 const float* __restrict__ wv,
                                                 float* __restrict__ v){
  const int w = threadIdx.x >> 6, lane = threadIdx.x & 63;
#pragma unroll
  for (int it = 0; it < 4; it++){
    const int row = blockIdx.x * 4 + w + it * 8192;
    float s = 0.f;
#pragma unroll
    for (int j = 0; j < 4; j++){
      const int c = lane * 4 + j * 256;
      float4 val = *(const float4*)(x + (size_t)row * 1024 + c);
      float4 wvv = *(const float4*)(wv + c);
      ushort4 h, l;
      split2(val.x, h.x, l.x); split2(val.y, h.y, l.y);
      split2(val.z, h.z, l.z); split2(val.w, h.w, l.w);
      *(ushort4*)(x2 + (size_t)row * 2048 + c) = h;
      *(ushort4*)(x2 + (size_t)row * 2048 + 1024 + c) = l;
      s += val.x * wvv.x + val.y * wvv.y + val.z * wvv.z + val.w * wvv.w;
    }
    for (int o = 32; o; o >>= 1) s += __shfl_xor(s, o);
    if (lane == 0) v[row] = s;
  }
}

// M = Wa*Wb^T 3-term split; write M^T split. grid 64.
__global__ __launch_bounds__(256) void k_gemm_mt(const unsigned short* __restrict__ Wa2,
                                                 const unsigned short* __restrict__ Wb2,
                                                 unsigned short* __restrict__ MT2){
  __shared__ __align__(16) unsigned short lsA[8192], lsB[8192];
  const int bm = blockIdx.x >> 3, bn = blockIdx.x & 7;
  f32x4 acc[4][4];
  gemm_core<1, 2>(Wa2 + (size_t)bm * 128 * 2048, 2048,
                  Wb2 + (size_t)bn * 128 * 2048, 2048, 3072, lsA, lsB, acc);
  const int tid = threadIdx.x, lane = tid & 63, w = tid >> 6;
  const int wr = (w >> 1) * 64, wc = (w & 1) * 64, l15 = lane & 15, lg = lane >> 4;
#pragma unroll
  for (int m = 0; m < 4; m++)
#pragma unroll
    for (int n = 0; n < 4; n++){
      const int g  = bn * 128 + wc + n * 16 + l15;
      const int f0 = bm * 128 + wr + m * 16 + lg * 4;
      ushort4 h4, l4;
      split2(acc[m][n][0], h4.x, l4.x); split2(acc[m][n][1], h4.y, l4.y);
      split2(acc[m][n][2], h4.z, l4.z); split2(acc[m][n][3], h4.w, l4.w);
      *(ushort4*)(MT2 + (size_t)g * 2048 + f0) = h4;
      *(ushort4*)(MT2 + (size_t)g * 2048 + 1024 + f0) = l4;
    }
}

// ---------- launcher ----------
extern "C" void kernel_launch(void* const* d_in, const int* in_sizes, int n_in,
                              void* d_out, int out_size, void* d_ws, size_t ws_size,
                              hipStream_t stream) {
  const float* x  = (const float*)d_in[0];
  const float* Wa = (const float*)d_in[2];
  const float* ba = (const float*)d_in[3];
  const float* Wb = (const float*)d_in[4];
  const float* Wg = (const float*)d_in[6];
  const float* bg = (const float*)d_in[7];

  unsigned short* x2  = (unsigned short*)d_ws;            // 32768 x 2048
  unsigned short* Wa2 = x2 + (size_t)32768 * 2048;        // 1024 x 2048
  unsigned short* Wb2 = Wa2 + (size_t)1024 * 2048;        // 1024 x 2048
  unsigned short* WgT = Wb2 + (size_t)1024 * 2048;        // 1024 x 2048
  unsigned short* MT2 = WgT + (size_t)1024 * 2048;        // 1024 x 2048
  unsigned short* FT  = MT2 + (size_t)1024 * 2048;        // 1024 x 32768 (feats^T bf16)
  float* wv = (float*)(FT + (size_t)1024 * 32768);        // 1024
  float* v  = wv + 1024;                                  // 32768
  size_t need = (size_t)((char*)(v + 32768) - (char*)d_ws);
  if (ws_size < need) return;

  unsigned short* y2 = (unsigned short*)d_out;            // y hi/lo in d_out until PV

  k_split   <<<1024, 256, 0, stream>>>(Wa, Wa2);
  k_split   <<<1024, 256, 0, stream>>>(Wb, Wb2);
  k_splitT  <<<1024, 256, 0, stream>>>(Wg, WgT);
  k_wv      <<<256,  256, 0, stream>>>(Wb, ba, wv);
  k_split_x <<<2048, 256, 0, stream>>>(x, x2, wv, v);
  k_gemm_mt <<<64,   256, 0, stream>>>(Wa2, Wb2, MT2);
  k_gemm256<0, 0, 16, 1><<<512, 512, 0, stream>>>(x2, WgT, FT, bg);      // featsT
  k_gemm256<1, 2, 48, 0><<<512, 512, 0, stream>>>(x2, MT2, y2, nullptr); // y = x*M
  k_frame   <<<256,  256, 0, stream>>>(y2, x2, v, FT, (float*)d_out);    // scores+softmax+PV
}

// Round 9
// 461.980 us; speedup vs baseline: 1.1489x; 1.1479x over previous
//
#include <hip/hip_runtime.h>

typedef __attribute__((ext_vector_type(8))) short bf16x8;   // raw 16B LDS load
typedef _Float16 f16x8 __attribute__((ext_vector_type(8)));
typedef __attribute__((ext_vector_type(4))) float f32x4;

// ---------- helpers ----------
__device__ __forceinline__ unsigned short f16b(float x){
  _Float16 h = (_Float16)x;
  return __builtin_bit_cast(unsigned short, h);
}
// fp16 2-term split: x = hi + lo + O(2^-22 |x|)
__device__ __forceinline__ void split2h(float x, unsigned short &hi, unsigned short &lo){
  _Float16 h = (_Float16)x;
  _Float16 l = (_Float16)(x - (float)h);
  hi = __builtin_bit_cast(unsigned short, h);
  lo = __builtin_bit_cast(unsigned short, l);
}
__device__ __forceinline__ void gload_lds16(const void* g, void* l){
  __builtin_amdgcn_global_load_lds((const __attribute__((address_space(1))) void*)g,
                                   (__attribute__((address_space(3))) void*)l, 16, 0, 0);
}
#define VM(N)    asm volatile("s_waitcnt vmcnt(" #N ")" ::: "memory")
#define LGKM0()  do { asm volatile("s_waitcnt lgkmcnt(0)" ::: "memory"); \
                      __builtin_amdgcn_sched_barrier(0); } while(0)
#define BAR()    do { __builtin_amdgcn_s_barrier(); \
                      __builtin_amdgcn_sched_barrier(0); } while(0)

// K-block remaps (buffers hold [hi | lo] at stride 2048, or single at 1024):
// MAP 0: identity. MAP 1: [hi|lo|hi]. MAP 2: [hi|hi|lo]. MAP 3: k mod 1024.
template<int MAP>
__device__ __forceinline__ int kmap(int k){
  if (MAP == 1) return (k < 2048) ? k : (k - 2048);
  if (MAP == 2) return (k < 1024) ? k : (k - 1024);
  if (MAP == 3) return k & 1023;
  return k;
}

// ============================================================================
// 256x256 fp16 GEMM, BK=64, 512 threads (8 waves 2x4), 2 LDS slots x 64KB.
// R5-measured schedule (best of 5 variants: 44.8% MfmaUtil): 2 barriers/tile.
// Stage quarters (2 gloads each): q0=A.k0, q1=B.k0, q2=B.k1, q3=A.k1,
// issued in phases P0..P3 of the PREVIOUS tile. Gate ledger (per-wave FIFO):
//   gate1(t) VM(4): out={q0..q3(t)}=8 -> retires q0,q1(t);  BAR certifies.
//   gate2(t) VM(4): out={q2,q3(t),q0,q1(t+1)}=8 -> retires q2,q3(t); BAR.
// XOR-swizzled LDS (verified 0 bank conflicts). lda/ldb runtime (elements).
// EPI 0: fp16 hi/lo split write, stride 2048 (y path).
// EPI 1: fp16(acc+bias[col]) transposed write, stride 32768 (featsT).
// EPI 2: fp16(acc) transposed write, stride 1024 (M^T).
// ============================================================================
template<int MAPA, int MAPB, int NK, int EPI>
__global__ __launch_bounds__(512, 2) void k_gemm256(
    const unsigned short* __restrict__ A, const unsigned short* __restrict__ B,
    unsigned short* __restrict__ outp, const float* __restrict__ bias,
    int lda, int ldb)
{
  __shared__ __align__(16) unsigned short lds_u[65536];   // 128 KiB
  char* ldsb = (char*)lds_u;

  int bid = blockIdx.x;                 // XCD-aware swizzle (grid % 8 == 0)
  bid = (bid & 7) * (gridDim.x >> 3) + (bid >> 3);
  const int bm = bid >> 2, bn = bid & 3;

  const int tid  = threadIdx.x;
  const int w    = tid >> 6;
  const int lane = tid & 63;
  const int wm   = w >> 2;              // 0..1
  const int wn   = w & 3;               // 0..3
  const int l15  = lane & 15;
  const int lg   = lane >> 4;

  // staging source map (inverse swizzle), 2 chunks per 16K region
  int srow[2], slg[2];
#pragma unroll
  for (int j = 0; j < 2; j++){
    int o16 = j * 512 + tid;
    int p = o16 >> 3, s = o16 & 7;
    int q = s ^ (p & 7);
    srow[j] = 2 * p + (q >> 2);
    slg[j]  = q & 3;
  }
  const unsigned short* aS0 = A + (size_t)(bm * 256 + srow[0]) * lda + slg[0] * 8;
  const unsigned short* aS1 = A + (size_t)(bm * 256 + srow[1]) * lda + slg[1] * 8;
  const unsigned short* bS0 = B + (size_t)(bn * 256 + srow[0]) * ldb + slg[0] * 8;
  const unsigned short* bS1 = B + (size_t)(bn * 256 + srow[1]) * ldb + slg[1] * 8;

  const int sA   = (((l15 & 1) << 2) | lg) ^ ((l15 >> 1) & 7);
  const int rps  = (l15 >> 1) * 128 + sA * 16;

  f32x4 acc[8][4];
  f32x4 zero = {0.f, 0.f, 0.f, 0.f};
#pragma unroll
  for (int m = 0; m < 8; m++)
#pragma unroll
    for (int n = 0; n < 4; n++) acc[m][n] = zero;

  auto STAGE_Q = [&](int t, int q){
    char* slot = ldsb + (size_t)(t & 1) * 65536;
    const int kbA = kmap<MAPA>(t * 64);
    const int kbB = kmap<MAPB>(t * 64);
    if (q == 0){
      gload_lds16(aS0 + kbA,      slot +         w * 1024);
      gload_lds16(aS1 + kbA,      slot +  8192 + w * 1024);
    } else if (q == 1){
      gload_lds16(bS0 + kbB,      slot + 32768 + w * 1024);
      gload_lds16(bS1 + kbB,      slot + 40960 + w * 1024);
    } else if (q == 2){
      gload_lds16(bS0 + kbB + 32, slot + 49152 + w * 1024);
      gload_lds16(bS1 + kbB + 32, slot + 57344 + w * 1024);
    } else {
      gload_lds16(aS0 + kbA + 32, slot + 16384 + w * 1024);
      gload_lds16(aS1 + kbA + 32, slot + 24576 + w * 1024);
    }
  };

  STAGE_Q(0, 0); STAGE_Q(0, 1); STAGE_Q(0, 2); STAGE_Q(0, 3);

#pragma unroll 1
  for (int t = 0; t < NK; t++){
    const char* sb = ldsb + (size_t)(t & 1) * 65536;
    const bool pre = (t + 1 < NK);
    f16x8 aF[4], bF[4], aG[4], bF2[4], aF2[4], aG2[4];

    VM(4);                              // gate1: q0,q1(t) landed
    BAR();
    // P0
    if (pre) STAGE_Q(t + 1, 0);
#pragma unroll
    for (int m = 0; m < 4; m++) aF[m] = *(const f16x8*)(sb + wm * 8192 + m * 1024 + rps);
#pragma unroll
    for (int n = 0; n < 4; n++) bF[n] = *(const f16x8*)(sb + 32768 + wn * 4096 + n * 1024 + rps);
    LGKM0();
    __builtin_amdgcn_s_setprio(1);
#pragma unroll
    for (int m = 0; m < 4; m++)
#pragma unroll
      for (int n = 0; n < 4; n++)
        acc[m][n] = __builtin_amdgcn_mfma_f32_16x16x32_f16(aF[m], bF[n], acc[m][n], 0, 0, 0);
    __builtin_amdgcn_s_setprio(0);
    // P1
    if (pre) STAGE_Q(t + 1, 1);
#pragma unroll
    for (int m = 0; m < 4; m++) aG[m] = *(const f16x8*)(sb + wm * 8192 + (m + 4) * 1024 + rps);
    LGKM0();
    __builtin_amdgcn_s_setprio(1);
#pragma unroll
    for (int m = 0; m < 4; m++)
#pragma unroll
      for (int n = 0; n < 4; n++)
        acc[m + 4][n] = __builtin_amdgcn_mfma_f32_16x16x32_f16(aG[m], bF[n], acc[m + 4][n], 0, 0, 0);
    __builtin_amdgcn_s_setprio(0);

    if (pre) { VM(4); } else { VM(0); } // gate2: q2,q3(t) landed
    BAR();
    // P2
    if (pre) STAGE_Q(t + 1, 2);
#pragma unroll
    for (int m = 0; m < 4; m++) aF2[m] = *(const f16x8*)(sb + 16384 + wm * 8192 + m * 1024 + rps);
#pragma unroll
    for (int n = 0; n < 4; n++) bF2[n] = *(const f16x8*)(sb + 49152 + wn * 4096 + n * 1024 + rps);
    LGKM0();
    __builtin_amdgcn_s_setprio(1);
#pragma unroll
    for (int m = 0; m < 4; m++)
#pragma unroll
      for (int n = 0; n < 4; n++)
        acc[m][n] = __builtin_amdgcn_mfma_f32_16x16x32_f16(aF2[m], bF2[n], acc[m][n], 0, 0, 0);
    __builtin_amdgcn_s_setprio(0);
    // P3
    if (pre) STAGE_Q(t + 1, 3);
#pragma unroll
    for (int m = 0; m < 4; m++) aG2[m] = *(const f16x8*)(sb + 16384 + wm * 8192 + (m + 4) * 1024 + rps);
    LGKM0();
    __builtin_amdgcn_s_setprio(1);
#pragma unroll
    for (int m = 0; m < 4; m++)
#pragma unroll
      for (int n = 0; n < 4; n++)
        acc[m + 4][n] = __builtin_amdgcn_mfma_f32_16x16x32_f16(aG2[m], bF2[n], acc[m + 4][n], 0, 0, 0);
    __builtin_amdgcn_s_setprio(0);
  }

#pragma unroll
  for (int m = 0; m < 8; m++)
#pragma unroll
    for (int n = 0; n < 4; n++){
      const int col  = bn * 256 + wn * 64 + n * 16 + l15;
      const int row0 = bm * 256 + wm * 128 + m * 16 + lg * 4;
      if (EPI == 0){
#pragma unroll
        for (int q = 0; q < 4; q++){
          unsigned short hi, lo; split2h(acc[m][n][q], hi, lo);
          const size_t base = (size_t)(row0 + q) * 2048;
          outp[base + col] = hi;
          outp[base + 1024 + col] = lo;
        }
      } else if (EPI == 1){
        const float bgv = bias[col];
        ushort4 h4;
        h4.x = f16b(acc[m][n][0] + bgv); h4.y = f16b(acc[m][n][1] + bgv);
        h4.z = f16b(acc[m][n][2] + bgv); h4.w = f16b(acc[m][n][3] + bgv);
        *(ushort4*)(outp + (size_t)col * 32768 + row0) = h4;
      } else {
        ushort4 h4;
        h4.x = f16b(acc[m][n][0]); h4.y = f16b(acc[m][n][1]);
        h4.z = f16b(acc[m][n][2]); h4.w = f16b(acc[m][n][3]);
        *(ushort4*)(outp + (size_t)col * 1024 + row0) = h4;
      }
    }
}

// ============================================================================
// Fused per-frame kernel: scores (K=3072, fp16 3-term) -> softmax -> PV.
// Structure identical to the verified R5 kernel; dtype fp16 throughout.
// ============================================================================
__global__ __launch_bounds__(256, 1) void k_frame(
    const unsigned short* Y2, const unsigned short* X2,
    const float* __restrict__ v, const unsigned short* __restrict__ FT,
    float* outp)
{
  __shared__ __align__(16) unsigned short lds_u[65536];   // 128 KiB
  char* ldsb = (char*)lds_u;

  const int frame = blockIdx.x;
  const int tid  = threadIdx.x;
  const int w    = tid >> 6;
  const int lane = tid & 63;
  const int wm   = w >> 1, wn = w & 1;
  const int l15  = lane & 15;
  const int lg   = lane >> 4;

  int srow[2], slg[2];
#pragma unroll
  for (int j = 0; j < 2; j++){
    int o = j * 256 + tid;
    int p = o >> 3, s = o & 7;
    int q = s ^ (p & 7);
    srow[j] = 2 * p + (q >> 2);
    slg[j]  = q & 3;
  }
  const unsigned short* yS0 = Y2 + (size_t)(frame * 128 + srow[0]) * 2048 + slg[0] * 8;
  const unsigned short* yS1 = Y2 + (size_t)(frame * 128 + srow[1]) * 2048 + slg[1] * 8;
  const unsigned short* xS0 = X2 + (size_t)(frame * 128 + srow[0]) * 2048 + slg[0] * 8;
  const unsigned short* xS1 = X2 + (size_t)(frame * 128 + srow[1]) * 2048 + slg[1] * 8;

  const int sA  = (((l15 & 1) << 2) | lg) ^ ((l15 >> 1) & 7);
  const int rps = (l15 >> 1) * 128 + sA * 16;

  f32x4 acc[4][4];
  f32x4 zero = {0.f, 0.f, 0.f, 0.f};
#pragma unroll
  for (int m = 0; m < 4; m++)
#pragma unroll
    for (int n = 0; n < 4; n++) acc[m][n] = zero;

  auto STAGE_K = [&](int t, int ks){
    char* slot = ldsb + (size_t)(t & 1) * 32768;
    const int kY = kmap<2>(t * 64) + ks * 32;   // A=Y: [yh|yh|yl]
    const int kX = kmap<1>(t * 64) + ks * 32;   // B=X: [xh|xl|xh]
    gload_lds16(yS0 + kY, slot + ks * 8192 +        tid * 16);
    gload_lds16(yS1 + kY, slot + ks * 8192 + 4096 + tid * 16);
    gload_lds16(xS0 + kX, slot + 16384 + ks * 8192 +        tid * 16);
    gload_lds16(xS1 + kX, slot + 16384 + ks * 8192 + 4096 + tid * 16);
  };

  const int NK = 48;
  STAGE_K(0, 0); STAGE_K(0, 1);

#pragma unroll 1
  for (int t = 0; t < NK; t++){
    const char* sb = ldsb + (size_t)(t & 1) * 32768;
    const bool pre = (t + 1 < NK);
    f16x8 aF[4], bF[4], aF2[4], bF2[4];

    VM(4);                      // gate1: k0(t) landed
    BAR();
    if (pre) STAGE_K(t + 1, 0);
#pragma unroll
    for (int m = 0; m < 4; m++) aF[m] = *(const f16x8*)(sb + wm * 4096 + m * 1024 + rps);
#pragma unroll
    for (int n = 0; n < 4; n++) bF[n] = *(const f16x8*)(sb + 16384 + wn * 4096 + n * 1024 + rps);
    LGKM0();
    __builtin_amdgcn_s_setprio(1);
#pragma unroll
    for (int m = 0; m < 4; m++)
#pragma unroll
      for (int n = 0; n < 4; n++)
        acc[m][n] = __builtin_amdgcn_mfma_f32_16x16x32_f16(aF[m], bF[n], acc[m][n], 0, 0, 0);
    __builtin_amdgcn_s_setprio(0);

    if (pre) { VM(4); } else { VM(0); } // gate2: k1(t) landed
    BAR();
    if (pre) STAGE_K(t + 1, 1);
#pragma unroll
    for (int m = 0; m < 4; m++) aF2[m] = *(const f16x8*)(sb + 8192 + wm * 4096 + m * 1024 + rps);
#pragma unroll
    for (int n = 0; n < 4; n++) bF2[n] = *(const f16x8*)(sb + 24576 + wn * 4096 + n * 1024 + rps);
    LGKM0();
    __builtin_amdgcn_s_setprio(1);
#pragma unroll
    for (int m = 0; m < 4; m++)
#pragma unroll
      for (int n = 0; n < 4; n++)
        acc[m][n] = __builtin_amdgcn_mfma_f32_16x16x32_f16(aF2[m], bF2[n], acc[m][n], 0, 0, 0);
    __builtin_amdgcn_s_setprio(0);
  }

  // ---- softmax: acc -> LDS fp32 (rotation swizzle), reduce, P fp16 to LDS ----
  BAR();
  float* sf = (float*)ldsb;
#pragma unroll
  for (int m = 0; m < 4; m++)
#pragma unroll
    for (int n = 0; n < 4; n++){
      const int col = wn * 64 + n * 16 + l15;
#pragma unroll
      for (int q = 0; q < 4; q++){
        const int row = wm * 64 + m * 16 + lg * 4 + q;
        sf[row * 128 + ((col + (row & 31) * 4) & 127)] = acc[m][n][q];
      }
    }
  LGKM0(); BAR();
  unsigned short* Pb = (unsigned short*)(ldsb + 65536);
  {
    const float* vr = v + (size_t)frame * 128;
#pragma unroll 1
    for (int i = 0; i < 32; i++){
      const int row = w * 32 + i;
      const float* rp = sf + row * 128;
      const int rot = (row & 31) * 4;
      float a = rp[(lane + rot) & 127]      + vr[lane];
      float b = rp[(lane + 64 + rot) & 127] + vr[lane + 64];
      float mx = fmaxf(a, b);
      for (int o = 32; o; o >>= 1) mx = fmaxf(mx, __shfl_xor(mx, o));
      float ea = __expf(a - mx), eb = __expf(b - mx);
      float s = ea + eb;
      for (int o = 32; o; o >>= 1) s += __shfl_xor(s, o);
      const float inv = 1.0f / s;
      unsigned short* prow = (unsigned short*)((char*)Pb + row * 256);
      const int j0 = lane, j1 = lane + 64;
      *(unsigned short*)((char*)prow + (((j0 >> 3) ^ (row & 15)) * 16) + (j0 & 7) * 2) = f16b(ea * inv);
      *(unsigned short*)((char*)prow + (((j1 >> 3) ^ (row & 15)) * 16) + (j1 & 7) * 2) = f16b(eb * inv);
    }
  }
  LGKM0(); BAR();

  // ---- PV: out[s][f] = sum_j P[s][j] * FT[f][frame*128+j] ----
  char* Fb = ldsb + 98304;
  auto STAGE_F = [&](int h){
    char* slot = Fb + (size_t)(h & 1) * 16384;
#pragma unroll
    for (int j = 0; j < 4; j++){
      const int o = j * 256 + tid;
      const int a = o >> 4, c = o & 15;
      gload_lds16(FT + (size_t)(h * 64 + a) * 32768 + frame * 128 + (c ^ (a & 15)) * 8,
                  slot + (size_t)o * 16);
    }
  };
  STAGE_F(0);

#pragma unroll 1
  for (int h = 0; h < 16; h++){
    VM(0);
    BAR();
    if (h + 1 < 16) STAGE_F(h + 1);
    const char* fs = Fb + (size_t)(h & 1) * 16384;
    f16x8 pF[4][4], fF[4][2];
#pragma unroll
    for (int ks = 0; ks < 4; ks++){
#pragma unroll
      for (int m = 0; m < 4; m++){
        const int row = wm * 64 + m * 16 + l15;
        pF[ks][m] = *(const f16x8*)((char*)Pb + row * 256 + (((ks * 4 + lg) ^ (row & 15)) * 16));
      }
#pragma unroll
      for (int n = 0; n < 2; n++){
        const int al = wn * 32 + n * 16 + l15;
        fF[ks][n] = *(const f16x8*)(fs + al * 256 + (((ks * 4 + lg) ^ (al & 15)) * 16));
      }
    }
    LGKM0();
    f32x4 accP[4][2];
#pragma unroll
    for (int m = 0; m < 4; m++)
#pragma unroll
      for (int n = 0; n < 2; n++) accP[m][n] = zero;
    __builtin_amdgcn_s_setprio(1);
#pragma unroll
    for (int ks = 0; ks < 4; ks++)
#pragma unroll
      for (int m = 0; m < 4; m++)
#pragma unroll
        for (int n = 0; n < 2; n++)
          accP[m][n] = __builtin_amdgcn_mfma_f32_16x16x32_f16(pF[ks][m], fF[ks][n], accP[m][n], 0, 0, 0);
    __builtin_amdgcn_s_setprio(0);
#pragma unroll
    for (int m = 0; m < 4; m++)
#pragma unroll
      for (int n = 0; n < 2; n++){
        const int f = h * 64 + wn * 32 + n * 16 + l15;
        const int r0 = wm * 64 + m * 16 + lg * 4;
#pragma unroll
        for (int q = 0; q < 4; q++)
          outp[((size_t)frame * 128 + r0 + q) * 1024 + f] = accP[m][n][q];
      }
  }
}

// ============================================================================
// Merged prep: blocks [0,1024) split Wa -> Wa2 (fp16 hi|lo, stride 2048);
// [1024,2048) Wb -> Wb2; [2048,3072) Wg row -> WgTh (fp16 single, transposed,
// stride 1024); [3072,3328) wv[f] = Wb[f,:] . ba (4 rows/block).
// ============================================================================
__global__ __launch_bounds__(256) void k_prep(const float* __restrict__ Wa,
                                              const float* __restrict__ Wb,
                                              const float* __restrict__ Wg,
                                              const float* __restrict__ ba,
                                              unsigned short* __restrict__ Wa2,
                                              unsigned short* __restrict__ Wb2,
                                              unsigned short* __restrict__ WgTh,
                                              float* __restrict__ wv){
  const int b = blockIdx.x;
  if (b < 2048){
    const int row = (b < 1024) ? b : (b - 1024);
    const float* src = (b < 1024) ? Wa : Wb;
    unsigned short* dst = (b < 1024) ? Wa2 : Wb2;
    const int c = threadIdx.x * 4;
    float4 val = *(const float4*)(src + (size_t)row * 1024 + c);
    ushort4 h, l;
    split2h(val.x, h.x, l.x); split2h(val.y, h.y, l.y);
    split2h(val.z, h.z, l.z); split2h(val.w, h.w, l.w);
    *(ushort4*)(dst + (size_t)row * 2048 + c) = h;
    *(ushort4*)(dst + (size_t)row * 2048 + 1024 + c) = l;
  } else if (b < 3072){
    const int row = b - 2048;                 // f index
    const int c0 = threadIdx.x * 4;           // a index base
    float4 val = *(const float4*)(Wg + (size_t)row * 1024 + c0);
    float vv[4] = {val.x, val.y, val.z, val.w};
#pragma unroll
    for (int i = 0; i < 4; i++)
      WgTh[(size_t)(c0 + i) * 1024 + row] = f16b(vv[i]);
  } else {
    const int row = (b - 3072) * 4 + (threadIdx.x >> 6);
    const int lane = threadIdx.x & 63;
    float s = 0.f;
#pragma unroll
    for (int j = 0; j < 4; j++){
      const int c = lane * 4 + j * 256;
      float4 wb = *(const float4*)(Wb + (size_t)row * 1024 + c);
      float4 bb = *(const float4*)(ba + c);
      s += wb.x * bb.x + wb.y * bb.y + wb.z * bb.z + wb.w * bb.w;
    }
    for (int o = 32; o; o >>= 1) s += __shfl_xor(s, o);
    if (lane == 0) wv[row] = s;
  }
}

// x split (fp16 hi|lo) + v[row] = x[row,:] . wv. One wave/row, 4/block. grid 2048.
__global__ __launch_bounds__(256) void k_split_x(const float* __restrict__ x,
                                                 unsigned short* __restrict__ x2,
                                                 const float* __restrict__ wv,
                                                 float* __restrict__ v){
  const int w = threadIdx.x >> 6, lane = threadIdx.x & 63;
#pragma unroll
  for (int it = 0; it < 4; it++){
    const int row = blockIdx.x * 4 + w + it * 8192;
    float s = 0.f;
#pragma unroll
    for (int j = 0; j < 4; j++){
      const int c = lane * 4 + j * 256;
      float4 val = *(const float4*)(x + (size_t)row * 1024 + c);
      float4 wvv = *(const float4*)(wv + c);
      ushort4 h, l;
      split2h(val.x, h.x, l.x); split2h(val.y, h.y, l.y);
      split2h(val.z, h.z, l.z); split2h(val.w, h.w, l.w);
      *(ushort4*)(x2 + (size_t)row * 2048 + c) = h;
      *(ushort4*)(x2 + (size_t)row * 2048 + 1024 + c) = l;
      s += val.x * wvv.x + val.y * wvv.y + val.z * wvv.z + val.w * wvv.w;
    }
    for (int o = 32; o; o >>= 1) s += __shfl_xor(s, o);
    if (lane == 0) v[row] = s;
  }
}

// ---------- launcher ----------
extern "C" void kernel_launch(void* const* d_in, const int* in_sizes, int n_in,
                              void* d_out, int out_size, void* d_ws, size_t ws_size,
                              hipStream_t stream) {
  const float* x  = (const float*)d_in[0];
  const float* Wa = (const float*)d_in[2];
  const float* ba = (const float*)d_in[3];
  const float* Wb = (const float*)d_in[4];
  const float* Wg = (const float*)d_in[6];
  const float* bg = (const float*)d_in[7];

  unsigned short* x2   = (unsigned short*)d_ws;            // 32768 x 2048 fp16 [xh|xl]
  unsigned short* Wa2  = x2 + (size_t)32768 * 2048;        // 1024 x 2048
  unsigned short* Wb2  = Wa2 + (size_t)1024 * 2048;        // 1024 x 2048
  unsigned short* WgTh = Wb2 + (size_t)1024 * 2048;        // 1024 x 1024 (Wg^T fp16)
  unsigned short* MTh  = WgTh + (size_t)1024 * 1024;       // 1024 x 1024 (M^T fp16)
  unsigned short* FT   = MTh + (size_t)1024 * 1024;        // 1024 x 32768 (feats^T fp16)
  float* wv = (float*)(FT + (size_t)1024 * 32768);         // 1024
  float* v  = wv + 1024;                                   // 32768
  size_t need = (size_t)((char*)(v + 32768) - (char*)d_ws);
  if (ws_size < need) return;

  unsigned short* y2 = (unsigned short*)d_out;             // y fp16 [yh|yl] until PV

  k_prep    <<<3328, 256, 0, stream>>>(Wa, Wb, Wg, ba, Wa2, Wb2, WgTh, wv);
  k_split_x <<<2048, 256, 0, stream>>>(x, x2, wv, v);
  // M = Wa*Wb^T, fp16 3-term: [h|l|h] x [h|h|l]; write M^T fp16 (EPI 2). grid 16.
  k_gemm256<1, 2, 48, 2><<<16,  512, 0, stream>>>(Wa2, Wb2, MTh, nullptr, 2048, 2048);
  // featsT = (xh*Wgh + bg)^T fp16 (EPI 1), K=1024. grid 512.
  k_gemm256<0, 0, 16, 1><<<512, 512, 0, stream>>>(x2, WgTh, FT, bg, 2048, 1024);
  // y = (xh+xl)*Mh, K=2048 (A identity over [xh|xl], B = Mh twice). EPI 0.
  k_gemm256<0, 3, 32, 0><<<512, 512, 0, stream>>>(x2, MTh, y2, nullptr, 2048, 1024);
  // scores (3-term fp16) -> softmax -> PV
  k_frame   <<<256,  256, 0, stream>>>(y2, x2, v, FT, (float*)d_out);
}

// Round 10
// 401.424 us; speedup vs baseline: 1.3222x; 1.1509x over previous
//
#include <hip/hip_runtime.h>

typedef __attribute__((ext_vector_type(8))) short bf16x8;   // raw 16B LDS load
typedef _Float16 f16x8 __attribute__((ext_vector_type(8)));
typedef __attribute__((ext_vector_type(4))) float f32x4;

// ---------- helpers ----------
__device__ __forceinline__ unsigned short f16b(float x){
  _Float16 h = (_Float16)x;
  return __builtin_bit_cast(unsigned short, h);
}
// fp16 2-term split: x = hi + lo + O(2^-22 |x|)
__device__ __forceinline__ void split2h(float x, unsigned short &hi, unsigned short &lo){
  _Float16 h = (_Float16)x;
  _Float16 l = (_Float16)(x - (float)h);
  hi = __builtin_bit_cast(unsigned short, h);
  lo = __builtin_bit_cast(unsigned short, l);
}
__device__ __forceinline__ void gload_lds16(const void* g, void* l){
  __builtin_amdgcn_global_load_lds((const __attribute__((address_space(1))) void*)g,
                                   (__attribute__((address_space(3))) void*)l, 16, 0, 0);
}
#define VM(N)    asm volatile("s_waitcnt vmcnt(" #N ")" ::: "memory")
#define LGKM0()  do { asm volatile("s_waitcnt lgkmcnt(0)" ::: "memory"); \
                      __builtin_amdgcn_sched_barrier(0); } while(0)
#define BAR()    do { __builtin_amdgcn_s_barrier(); \
                      __builtin_amdgcn_sched_barrier(0); } while(0)

// K-block remaps: MAP 0 identity; MAP 1 [hi|lo|hi]; MAP 2 [hi|hi|lo]; MAP 3 k mod 1024.
template<int MAP>
__device__ __forceinline__ int kmap(int k){
  if (MAP == 1) return (k < 2048) ? k : (k - 2048);
  if (MAP == 2) return (k < 1024) ? k : (k - 1024);
  if (MAP == 3) return k & 1023;
  return k;
}

// ============================================================================
// 256x256 fp16 GEMM, BK=64, 512 threads (8 waves 2x4), 2 LDS slots x 64KB.
// R5-measured schedule (best of 5 variants): 2 barriers/tile, gate ledger:
//   gate1(t) VM(4) retires q0,q1(t); gate2(t) VM(4) retires q2,q3(t);
//   each gate precedes its BAR -> cross-wave certified. XOR-swizzled LDS
//   (verified 0 bank conflicts). lda/ldb runtime (elements).
// EPI 0: fp16 hi/lo split write, stride 2048.
// EPI 1: fp16(acc+bias[col]) transposed write, stride 32768 (featsT).
// EPI 2: fp16(acc) transposed write, stride 1024 (M^T).
// EPI 3: fp16(acc) DUPLICATED into both halves, stride 2048 (y path).
// ============================================================================
template<int MAPA, int MAPB, int NK, int EPI>
__global__ __launch_bounds__(512, 2) void k_gemm256(
    const unsigned short* __restrict__ A, const unsigned short* __restrict__ B,
    unsigned short* __restrict__ outp, const float* __restrict__ bias,
    int lda, int ldb)
{
  __shared__ __align__(16) unsigned short lds_u[65536];   // 128 KiB
  char* ldsb = (char*)lds_u;

  int bid = blockIdx.x;                 // XCD-aware swizzle (grid % 8 == 0)
  bid = (bid & 7) * (gridDim.x >> 3) + (bid >> 3);
  const int bm = bid >> 2, bn = bid & 3;

  const int tid  = threadIdx.x;
  const int w    = tid >> 6;
  const int lane = tid & 63;
  const int wm   = w >> 2;              // 0..1
  const int wn   = w & 3;               // 0..3
  const int l15  = lane & 15;
  const int lg   = lane >> 4;

  // staging source map (inverse swizzle), 2 chunks per 16K region
  int srow[2], slg[2];
#pragma unroll
  for (int j = 0; j < 2; j++){
    int o16 = j * 512 + tid;
    int p = o16 >> 3, s = o16 & 7;
    int q = s ^ (p & 7);
    srow[j] = 2 * p + (q >> 2);
    slg[j]  = q & 3;
  }
  const unsigned short* aS0 = A + (size_t)(bm * 256 + srow[0]) * lda + slg[0] * 8;
  const unsigned short* aS1 = A + (size_t)(bm * 256 + srow[1]) * lda + slg[1] * 8;
  const unsigned short* bS0 = B + (size_t)(bn * 256 + srow[0]) * ldb + slg[0] * 8;
  const unsigned short* bS1 = B + (size_t)(bn * 256 + srow[1]) * ldb + slg[1] * 8;

  const int sA   = (((l15 & 1) << 2) | lg) ^ ((l15 >> 1) & 7);
  const int rps  = (l15 >> 1) * 128 + sA * 16;

  f32x4 acc[8][4];
  f32x4 zero = {0.f, 0.f, 0.f, 0.f};
#pragma unroll
  for (int m = 0; m < 8; m++)
#pragma unroll
    for (int n = 0; n < 4; n++) acc[m][n] = zero;

  auto STAGE_Q = [&](int t, int q){
    char* slot = ldsb + (size_t)(t & 1) * 65536;
    const int kbA = kmap<MAPA>(t * 64);
    const int kbB = kmap<MAPB>(t * 64);
    if (q == 0){
      gload_lds16(aS0 + kbA,      slot +         w * 1024);
      gload_lds16(aS1 + kbA,      slot +  8192 + w * 1024);
    } else if (q == 1){
      gload_lds16(bS0 + kbB,      slot + 32768 + w * 1024);
      gload_lds16(bS1 + kbB,      slot + 40960 + w * 1024);
    } else if (q == 2){
      gload_lds16(bS0 + kbB + 32, slot + 49152 + w * 1024);
      gload_lds16(bS1 + kbB + 32, slot + 57344 + w * 1024);
    } else {
      gload_lds16(aS0 + kbA + 32, slot + 16384 + w * 1024);
      gload_lds16(aS1 + kbA + 32, slot + 24576 + w * 1024);
    }
  };

  STAGE_Q(0, 0); STAGE_Q(0, 1); STAGE_Q(0, 2); STAGE_Q(0, 3);

#pragma unroll 1
  for (int t = 0; t < NK; t++){
    const char* sb = ldsb + (size_t)(t & 1) * 65536;
    const bool pre = (t + 1 < NK);
    f16x8 aF[4], bF[4], aG[4], bF2[4], aF2[4], aG2[4];

    VM(4);                              // gate1: q0,q1(t) landed
    BAR();
    // P0
    if (pre) STAGE_Q(t + 1, 0);
#pragma unroll
    for (int m = 0; m < 4; m++) aF[m] = *(const f16x8*)(sb + wm * 8192 + m * 1024 + rps);
#pragma unroll
    for (int n = 0; n < 4; n++) bF[n] = *(const f16x8*)(sb + 32768 + wn * 4096 + n * 1024 + rps);
    LGKM0();
    __builtin_amdgcn_s_setprio(1);
#pragma unroll
    for (int m = 0; m < 4; m++)
#pragma unroll
      for (int n = 0; n < 4; n++)
        acc[m][n] = __builtin_amdgcn_mfma_f32_16x16x32_f16(aF[m], bF[n], acc[m][n], 0, 0, 0);
    __builtin_amdgcn_s_setprio(0);
    // P1
    if (pre) STAGE_Q(t + 1, 1);
#pragma unroll
    for (int m = 0; m < 4; m++) aG[m] = *(const f16x8*)(sb + wm * 8192 + (m + 4) * 1024 + rps);
    LGKM0();
    __builtin_amdgcn_s_setprio(1);
#pragma unroll
    for (int m = 0; m < 4; m++)
#pragma unroll
      for (int n = 0; n < 4; n++)
        acc[m + 4][n] = __builtin_amdgcn_mfma_f32_16x16x32_f16(aG[m], bF[n], acc[m + 4][n], 0, 0, 0);
    __builtin_amdgcn_s_setprio(0);

    if (pre) { VM(4); } else { VM(0); } // gate2: q2,q3(t) landed
    BAR();
    // P2
    if (pre) STAGE_Q(t + 1, 2);
#pragma unroll
    for (int m = 0; m < 4; m++) aF2[m] = *(const f16x8*)(sb + 16384 + wm * 8192 + m * 1024 + rps);
#pragma unroll
    for (int n = 0; n < 4; n++) bF2[n] = *(const f16x8*)(sb + 49152 + wn * 4096 + n * 1024 + rps);
    LGKM0();
    __builtin_amdgcn_s_setprio(1);
#pragma unroll
    for (int m = 0; m < 4; m++)
#pragma unroll
      for (int n = 0; n < 4; n++)
        acc[m][n] = __builtin_amdgcn_mfma_f32_16x16x32_f16(aF2[m], bF2[n], acc[m][n], 0, 0, 0);
    __builtin_amdgcn_s_setprio(0);
    // P3
    if (pre) STAGE_Q(t + 1, 3);
#pragma unroll
    for (int m = 0; m < 4; m++) aG2[m] = *(const f16x8*)(sb + 16384 + wm * 8192 + (m + 4) * 1024 + rps);
    LGKM0();
    __builtin_amdgcn_s_setprio(1);
#pragma unroll
    for (int m = 0; m < 4; m++)
#pragma unroll
      for (int n = 0; n < 4; n++)
        acc[m + 4][n] = __builtin_amdgcn_mfma_f32_16x16x32_f16(aG2[m], bF2[n], acc[m + 4][n], 0, 0, 0);
    __builtin_amdgcn_s_setprio(0);
  }

#pragma unroll
  for (int m = 0; m < 8; m++)
#pragma unroll
    for (int n = 0; n < 4; n++){
      const int col  = bn * 256 + wn * 64 + n * 16 + l15;
      const int row0 = bm * 256 + wm * 128 + m * 16 + lg * 4;
      if (EPI == 0){
#pragma unroll
        for (int q = 0; q < 4; q++){
          unsigned short hi, lo; split2h(acc[m][n][q], hi, lo);
          const size_t base = (size_t)(row0 + q) * 2048;
          outp[base + col] = hi;
          outp[base + 1024 + col] = lo;
        }
      } else if (EPI == 1){
        const float bgv = bias[col];
        ushort4 h4;
        h4.x = f16b(acc[m][n][0] + bgv); h4.y = f16b(acc[m][n][1] + bgv);
        h4.z = f16b(acc[m][n][2] + bgv); h4.w = f16b(acc[m][n][3] + bgv);
        *(ushort4*)(outp + (size_t)col * 32768 + row0) = h4;
      } else if (EPI == 2){
        ushort4 h4;
        h4.x = f16b(acc[m][n][0]); h4.y = f16b(acc[m][n][1]);
        h4.z = f16b(acc[m][n][2]); h4.w = f16b(acc[m][n][3]);
        *(ushort4*)(outp + (size_t)col * 1024 + row0) = h4;
      } else {                            // EPI 3: duplicated-hi y write
#pragma unroll
        for (int q = 0; q < 4; q++){
          const unsigned short hv = f16b(acc[m][n][q]);
          const size_t base = (size_t)(row0 + q) * 2048;
          outp[base + col] = hv;
          outp[base + 1024 + col] = hv;
        }
      }
    }
}

// ============================================================================
// Fused per-frame kernel: scores (K=2048: [yh|yh] x [xh|xl]) -> softmax -> PV.
// Structure identical to the verified R5/R9 kernel; NK 48->32, identity maps.
// ============================================================================
__global__ __launch_bounds__(256, 1) void k_frame(
    const unsigned short* Y2, const unsigned short* X2,
    const float* __restrict__ v, const unsigned short* __restrict__ FT,
    float* outp)
{
  __shared__ __align__(16) unsigned short lds_u[65536];   // 128 KiB
  char* ldsb = (char*)lds_u;

  const int frame = blockIdx.x;
  const int tid  = threadIdx.x;
  const int w    = tid >> 6;
  const int lane = tid & 63;
  const int wm   = w >> 1, wn = w & 1;
  const int l15  = lane & 15;
  const int lg   = lane >> 4;

  int srow[2], slg[2];
#pragma unroll
  for (int j = 0; j < 2; j++){
    int o = j * 256 + tid;
    int p = o >> 3, s = o & 7;
    int q = s ^ (p & 7);
    srow[j] = 2 * p + (q >> 2);
    slg[j]  = q & 3;
  }
  const unsigned short* yS0 = Y2 + (size_t)(frame * 128 + srow[0]) * 2048 + slg[0] * 8;
  const unsigned short* yS1 = Y2 + (size_t)(frame * 128 + srow[1]) * 2048 + slg[1] * 8;
  const unsigned short* xS0 = X2 + (size_t)(frame * 128 + srow[0]) * 2048 + slg[0] * 8;
  const unsigned short* xS1 = X2 + (size_t)(frame * 128 + srow[1]) * 2048 + slg[1] * 8;

  const int sA  = (((l15 & 1) << 2) | lg) ^ ((l15 >> 1) & 7);
  const int rps = (l15 >> 1) * 128 + sA * 16;

  f32x4 acc[4][4];
  f32x4 zero = {0.f, 0.f, 0.f, 0.f};
#pragma unroll
  for (int m = 0; m < 4; m++)
#pragma unroll
    for (int n = 0; n < 4; n++) acc[m][n] = zero;

  auto STAGE_K = [&](int t, int ks){
    char* slot = ldsb + (size_t)(t & 1) * 32768;
    const int kk = t * 64 + ks * 32;            // identity maps both sides
    gload_lds16(yS0 + kk, slot + ks * 8192 +        tid * 16);
    gload_lds16(yS1 + kk, slot + ks * 8192 + 4096 + tid * 16);
    gload_lds16(xS0 + kk, slot + 16384 + ks * 8192 +        tid * 16);
    gload_lds16(xS1 + kk, slot + 16384 + ks * 8192 + 4096 + tid * 16);
  };

  const int NK = 32;
  STAGE_K(0, 0); STAGE_K(0, 1);

#pragma unroll 1
  for (int t = 0; t < NK; t++){
    const char* sb = ldsb + (size_t)(t & 1) * 32768;
    const bool pre = (t + 1 < NK);
    f16x8 aF[4], bF[4], aF2[4], bF2[4];

    VM(4);                      // gate1: k0(t) landed
    BAR();
    if (pre) STAGE_K(t + 1, 0);
#pragma unroll
    for (int m = 0; m < 4; m++) aF[m] = *(const f16x8*)(sb + wm * 4096 + m * 1024 + rps);
#pragma unroll
    for (int n = 0; n < 4; n++) bF[n] = *(const f16x8*)(sb + 16384 + wn * 4096 + n * 1024 + rps);
    LGKM0();
    __builtin_amdgcn_s_setprio(1);
#pragma unroll
    for (int m = 0; m < 4; m++)
#pragma unroll
      for (int n = 0; n < 4; n++)
        acc[m][n] = __builtin_amdgcn_mfma_f32_16x16x32_f16(aF[m], bF[n], acc[m][n], 0, 0, 0);
    __builtin_amdgcn_s_setprio(0);

    if (pre) { VM(4); } else { VM(0); } // gate2: k1(t) landed
    BAR();
    if (pre) STAGE_K(t + 1, 1);
#pragma unroll
    for (int m = 0; m < 4; m++) aF2[m] = *(const f16x8*)(sb + 8192 + wm * 4096 + m * 1024 + rps);
#pragma unroll
    for (int n = 0; n < 4; n++) bF2[n] = *(const f16x8*)(sb + 24576 + wn * 4096 + n * 1024 + rps);
    LGKM0();
    __builtin_amdgcn_s_setprio(1);
#pragma unroll
    for (int m = 0; m < 4; m++)
#pragma unroll
      for (int n = 0; n < 4; n++)
        acc[m][n] = __builtin_amdgcn_mfma_f32_16x16x32_f16(aF2[m], bF2[n], acc[m][n], 0, 0, 0);
    __builtin_amdgcn_s_setprio(0);
  }

  // ---- softmax: acc -> LDS fp32 (rotation swizzle), reduce, P fp16 to LDS ----
  BAR();
  float* sf = (float*)ldsb;
#pragma unroll
  for (int m = 0; m < 4; m++)
#pragma unroll
    for (int n = 0; n < 4; n++){
      const int col = wn * 64 + n * 16 + l15;
#pragma unroll
      for (int q = 0; q < 4; q++){
        const int row = wm * 64 + m * 16 + lg * 4 + q;
        sf[row * 128 + ((col + (row & 31) * 4) & 127)] = acc[m][n][q];
      }
    }
  LGKM0(); BAR();
  unsigned short* Pb = (unsigned short*)(ldsb + 65536);
  {
    const float* vr = v + (size_t)frame * 128;
#pragma unroll 1
    for (int i = 0; i < 32; i++){
      const int row = w * 32 + i;
      const float* rp = sf + row * 128;
      const int rot = (row & 31) * 4;
      float a = rp[(lane + rot) & 127]      + vr[lane];
      float b = rp[(lane + 64 + rot) & 127] + vr[lane + 64];
      float mx = fmaxf(a, b);
      for (int o = 32; o; o >>= 1) mx = fmaxf(mx, __shfl_xor(mx, o));
      float ea = __expf(a - mx), eb = __expf(b - mx);
      float s = ea + eb;
      for (int o = 32; o; o >>= 1) s += __shfl_xor(s, o);
      const float inv = 1.0f / s;
      unsigned short* prow = (unsigned short*)((char*)Pb + row * 256);
      const int j0 = lane, j1 = lane + 64;
      *(unsigned short*)((char*)prow + (((j0 >> 3) ^ (row & 15)) * 16) + (j0 & 7) * 2) = f16b(ea * inv);
      *(unsigned short*)((char*)prow + (((j1 >> 3) ^ (row & 15)) * 16) + (j1 & 7) * 2) = f16b(eb * inv);
    }
  }
  LGKM0(); BAR();

  // ---- PV: out[s][f] = sum_j P[s][j] * FT[f][frame*128+j] ----
  char* Fb = ldsb + 98304;
  auto STAGE_F = [&](int h){
    char* slot = Fb + (size_t)(h & 1) * 16384;
#pragma unroll
    for (int j = 0; j < 4; j++){
      const int o = j * 256 + tid;
      const int a = o >> 4, c = o & 15;
      gload_lds16(FT + (size_t)(h * 64 + a) * 32768 + frame * 128 + (c ^ (a & 15)) * 8,
                  slot + (size_t)o * 16);
    }
  };
  STAGE_F(0);

#pragma unroll 1
  for (int h = 0; h < 16; h++){
    VM(0);
    BAR();
    if (h + 1 < 16) STAGE_F(h + 1);
    const char* fs = Fb + (size_t)(h & 1) * 16384;
    f16x8 pF[4][4], fF[4][2];
#pragma unroll
    for (int ks = 0; ks < 4; ks++){
#pragma unroll
      for (int m = 0; m < 4; m++){
        const int row = wm * 64 + m * 16 + l15;
        pF[ks][m] = *(const f16x8*)((char*)Pb + row * 256 + (((ks * 4 + lg) ^ (row & 15)) * 16));
      }
#pragma unroll
      for (int n = 0; n < 2; n++){
        const int al = wn * 32 + n * 16 + l15;
        fF[ks][n] = *(const f16x8*)(fs + al * 256 + (((ks * 4 + lg) ^ (al & 15)) * 16));
      }
    }
    LGKM0();
    f32x4 accP[4][2];
#pragma unroll
    for (int m = 0; m < 4; m++)
#pragma unroll
      for (int n = 0; n < 2; n++) accP[m][n] = zero;
    __builtin_amdgcn_s_setprio(1);
#pragma unroll
    for (int ks = 0; ks < 4; ks++)
#pragma unroll
      for (int m = 0; m < 4; m++)
#pragma unroll
        for (int n = 0; n < 2; n++)
          accP[m][n] = __builtin_amdgcn_mfma_f32_16x16x32_f16(pF[ks][m], fF[ks][n], accP[m][n], 0, 0, 0);
    __builtin_amdgcn_s_setprio(0);
#pragma unroll
    for (int m = 0; m < 4; m++)
#pragma unroll
      for (int n = 0; n < 2; n++){
        const int f = h * 64 + wn * 32 + n * 16 + l15;
        const int r0 = wm * 64 + m * 16 + lg * 4;
#pragma unroll
        for (int q = 0; q < 4; q++)
          outp[((size_t)frame * 128 + r0 + q) * 1024 + f] = accP[m][n][q];
      }
  }
}

// ============================================================================
// Merged prep (unchanged from R9).
// ============================================================================
__global__ __launch_bounds__(256) void k_prep(const float* __restrict__ Wa,
                                              const float* __restrict__ Wb,
                                              const float* __restrict__ Wg,
                                              const float* __restrict__ ba,
                                              unsigned short* __restrict__ Wa2,
                                              unsigned short* __restrict__ Wb2,
                                              unsigned short* __restrict__ WgTh,
                                              float* __restrict__ wv){
  const int b = blockIdx.x;
  if (b < 2048){
    const int row = (b < 1024) ? b : (b - 1024);
    const float* src = (b < 1024) ? Wa : Wb;
    unsigned short* dst = (b < 1024) ? Wa2 : Wb2;
    const int c = threadIdx.x * 4;
    float4 val = *(const float4*)(src + (size_t)row * 1024 + c);
    ushort4 h, l;
    split2h(val.x, h.x, l.x); split2h(val.y, h.y, l.y);
    split2h(val.z, h.z, l.z); split2h(val.w, h.w, l.w);
    *(ushort4*)(dst + (size_t)row * 2048 + c) = h;
    *(ushort4*)(dst + (size_t)row * 2048 + 1024 + c) = l;
  } else if (b < 3072){
    const int row = b - 2048;                 // f index
    const int c0 = threadIdx.x * 4;           // a index base
    float4 val = *(const float4*)(Wg + (size_t)row * 1024 + c0);
    float vv[4] = {val.x, val.y, val.z, val.w};
#pragma unroll
    for (int i = 0; i < 4; i++)
      WgTh[(size_t)(c0 + i) * 1024 + row] = f16b(vv[i]);
  } else {
    const int row = (b - 3072) * 4 + (threadIdx.x >> 6);
    const int lane = threadIdx.x & 63;
    float s = 0.f;
#pragma unroll
    for (int j = 0; j < 4; j++){
      const int c = lane * 4 + j * 256;
      float4 wb = *(const float4*)(Wb + (size_t)row * 1024 + c);
      float4 bb = *(const float4*)(ba + c);
      s += wb.x * bb.x + wb.y * bb.y + wb.z * bb.z + wb.w * bb.w;
    }
    for (int o = 32; o; o >>= 1) s += __shfl_xor(s, o);
    if (lane == 0) wv[row] = s;
  }
}

// x split (fp16 hi|lo) + v[row] = x[row,:] . wv. One wave/row, 4/block. grid 2048.
__global__ __launch_bounds__(256) void k_split_x(const float* __restrict__ x,
                                                 unsigned short* __restrict__ x2,
                                                 const float* __restrict__ wv,
                                                 float* __restrict__ v){
  const int w = threadIdx.x >> 6, lane = threadIdx.x & 63;
#pragma unroll
  for (int it = 0; it < 4; it++){
    const int row = blockIdx.x * 4 + w + it * 8192;
    float s = 0.f;
#pragma unroll
    for (int j = 0; j < 4; j++){
      const int c = lane * 4 + j * 256;
      float4 val = *(const float4*)(x + (size_t)row * 1024 + c);
      float4 wvv = *(const float4*)(wv + c);
      ushort4 h, l;
      split2h(val.x, h.x, l.x); split2h(val.y, h.y, l.y);
      split2h(val.z, h.z, l.z); split2h(val.w, h.w, l.w);
      *(ushort4*)(x2 + (size_t)row * 2048 + c) = h;
      *(ushort4*)(x2 + (size_t)row * 2048 + 1024 + c) = l;
      s += val.x * wvv.x + val.y * wvv.y + val.z * wvv.z + val.w * wvv.w;
    }
    for (int o = 32; o; o >>= 1) s += __shfl_xor(s, o);
    if (lane == 0) v[row] = s;
  }
}

// ---------- launcher ----------
extern "C" void kernel_launch(void* const* d_in, const int* in_sizes, int n_in,
                              void* d_out, int out_size, void* d_ws, size_t ws_size,
                              hipStream_t stream) {
  const float* x  = (const float*)d_in[0];
  const float* Wa = (const float*)d_in[2];
  const float* ba = (const float*)d_in[3];
  const float* Wb = (const float*)d_in[4];
  const float* Wg = (const float*)d_in[6];
  const float* bg = (const float*)d_in[7];

  unsigned short* x2   = (unsigned short*)d_ws;            // 32768 x 2048 fp16 [xh|xl]
  unsigned short* Wa2  = x2 + (size_t)32768 * 2048;        // 1024 x 2048
  unsigned short* Wb2  = Wa2 + (size_t)1024 * 2048;        // 1024 x 2048
  unsigned short* WgTh = Wb2 + (size_t)1024 * 2048;        // 1024 x 1024 (Wg^T fp16)
  unsigned short* MTh  = WgTh + (size_t)1024 * 1024;       // 1024 x 1024 (M^T fp16)
  unsigned short* FT   = MTh + (size_t)1024 * 1024;        // 1024 x 32768 (feats^T fp16)
  float* wv = (float*)(FT + (size_t)1024 * 32768);         // 1024
  float* v  = wv + 1024;                                   // 32768
  size_t need = (size_t)((char*)(v + 32768) - (char*)d_ws);
  if (ws_size < need) return;

  unsigned short* y2 = (unsigned short*)d_out;             // y fp16 [yh|yh] until PV

  k_prep    <<<3328, 256, 0, stream>>>(Wa, Wb, Wg, ba, Wa2, Wb2, WgTh, wv);
  k_split_x <<<2048, 256, 0, stream>>>(x, x2, wv, v);
  // M = Wa*Wb^T, fp16 3-term: [h|l|h] x [h|h|l]; write M^T fp16 (EPI 2). grid 16.
  k_gemm256<1, 2, 48, 2><<<16,  512, 0, stream>>>(Wa2, Wb2, MTh, nullptr, 2048, 2048);
  // featsT = (xh*Wgh + bg)^T fp16 (EPI 1), K=1024. grid 512.
  k_gemm256<0, 0, 16, 1><<<512, 512, 0, stream>>>(x2, WgTh, FT, bg, 2048, 1024);
  // y = xh*Mh, K=1024; write yh duplicated into both halves (EPI 3). grid 512.
  k_gemm256<0, 0, 16, 3><<<512, 512, 0, stream>>>(x2, MTh, y2, nullptr, 2048, 1024);
  // scores (K=2048: [yh|yh] x [xh|xl]) -> softmax -> PV
  k_frame   <<<256,  256, 0, stream>>>(y2, x2, v, FT, (float*)d_out);
}

// Round 11
// 380.093 us; speedup vs baseline: 1.3964x; 1.0561x over previous
//
#include <hip/hip_runtime.h>

typedef _Float16 f16x8 __attribute__((ext_vector_type(8)));
typedef __attribute__((ext_vector_type(4))) float f32x4;

// ---------- helpers ----------
__device__ __forceinline__ unsigned short f16b(float x){
  _Float16 h = (_Float16)x;
  return __builtin_bit_cast(unsigned short, h);
}
// fp16 2-term split: x = hi + lo + O(2^-22 |x|)
__device__ __forceinline__ void split2h(float x, unsigned short &hi, unsigned short &lo){
  _Float16 h = (_Float16)x;
  _Float16 l = (_Float16)(x - (float)h);
  hi = __builtin_bit_cast(unsigned short, h);
  lo = __builtin_bit_cast(unsigned short, l);
}
__device__ __forceinline__ void gload_lds16(const void* g, void* l){
  __builtin_amdgcn_global_load_lds((const __attribute__((address_space(1))) void*)g,
                                   (__attribute__((address_space(3))) void*)l, 16, 0, 0);
}
#define VM(N)    asm volatile("s_waitcnt vmcnt(" #N ")" ::: "memory")
#define LGKM0()  do { asm volatile("s_waitcnt lgkmcnt(0)" ::: "memory"); \
                      __builtin_amdgcn_sched_barrier(0); } while(0)
#define BAR()    do { __builtin_amdgcn_s_barrier(); \
                      __builtin_amdgcn_sched_barrier(0); } while(0)

// K-block remaps: MAP 0 identity; MAP 1 [hi|lo|hi]; MAP 2 [hi|hi|lo]; MAP 3 k mod 1024.
template<int MAP>
__device__ __forceinline__ int kmap(int k){
  if (MAP == 1) return (k < 2048) ? k : (k - 2048);
  if (MAP == 2) return (k < 1024) ? k : (k - 1024);
  if (MAP == 3) return k & 1023;
  return k;
}

// ============================================================================
// 256x256 fp16 GEMM, BK=64, 512 threads (8 waves 2x4), 2 LDS slots x 64KB.
// R5-measured schedule (best of 5 variants): 2 barriers/tile, gate ledger:
//   gate1(t) VM(4) retires q0,q1(t); gate2(t) VM(4) retires q2,q3(t);
//   each gate precedes its BAR -> cross-wave certified. XOR-swizzled LDS
//   (verified 0 bank conflicts). lda/ldb runtime (elements).
// EPI 0: fp16 hi/lo split write, stride 2048.
// EPI 1: fp16(acc+bias[col]) transposed write, stride 32768 (featsT).
// EPI 2: fp16(acc) transposed write, stride 1024 (M^T).
// EPI 4: fp16(acc) row-major single write, stride 2048 (y path, half-filled).
// ============================================================================
template<int MAPA, int MAPB, int NK, int EPI>
__global__ __launch_bounds__(512, 2) void k_gemm256(
    const unsigned short* __restrict__ A, const unsigned short* __restrict__ B,
    unsigned short* __restrict__ outp, const float* __restrict__ bias,
    int lda, int ldb)
{
  __shared__ __align__(16) unsigned short lds_u[65536];   // 128 KiB
  char* ldsb = (char*)lds_u;

  int bid = blockIdx.x;                 // XCD-aware swizzle (grid % 8 == 0)
  bid = (bid & 7) * (gridDim.x >> 3) + (bid >> 3);
  const int bm = bid >> 2, bn = bid & 3;

  const int tid  = threadIdx.x;
  const int w    = tid >> 6;
  const int lane = tid & 63;
  const int wm   = w >> 2;              // 0..1
  const int wn   = w & 3;               // 0..3
  const int l15  = lane & 15;
  const int lg   = lane >> 4;

  // staging source map (inverse swizzle), 2 chunks per 16K region
  int srow[2], slg[2];
#pragma unroll
  for (int j = 0; j < 2; j++){
    int o16 = j * 512 + tid;
    int p = o16 >> 3, s = o16 & 7;
    int q = s ^ (p & 7);
    srow[j] = 2 * p + (q >> 2);
    slg[j]  = q & 3;
  }
  const unsigned short* aS0 = A + (size_t)(bm * 256 + srow[0]) * lda + slg[0] * 8;
  const unsigned short* aS1 = A + (size_t)(bm * 256 + srow[1]) * lda + slg[1] * 8;
  const unsigned short* bS0 = B + (size_t)(bn * 256 + srow[0]) * ldb + slg[0] * 8;
  const unsigned short* bS1 = B + (size_t)(bn * 256 + srow[1]) * ldb + slg[1] * 8;

  const int sA   = (((l15 & 1) << 2) | lg) ^ ((l15 >> 1) & 7);
  const int rps  = (l15 >> 1) * 128 + sA * 16;

  f32x4 acc[8][4];
  f32x4 zero = {0.f, 0.f, 0.f, 0.f};
#pragma unroll
  for (int m = 0; m < 8; m++)
#pragma unroll
    for (int n = 0; n < 4; n++) acc[m][n] = zero;

  auto STAGE_Q = [&](int t, int q){
    char* slot = ldsb + (size_t)(t & 1) * 65536;
    const int kbA = kmap<MAPA>(t * 64);
    const int kbB = kmap<MAPB>(t * 64);
    if (q == 0){
      gload_lds16(aS0 + kbA,      slot +         w * 1024);
      gload_lds16(aS1 + kbA,      slot +  8192 + w * 1024);
    } else if (q == 1){
      gload_lds16(bS0 + kbB,      slot + 32768 + w * 1024);
      gload_lds16(bS1 + kbB,      slot + 40960 + w * 1024);
    } else if (q == 2){
      gload_lds16(bS0 + kbB + 32, slot + 49152 + w * 1024);
      gload_lds16(bS1 + kbB + 32, slot + 57344 + w * 1024);
    } else {
      gload_lds16(aS0 + kbA + 32, slot + 16384 + w * 1024);
      gload_lds16(aS1 + kbA + 32, slot + 24576 + w * 1024);
    }
  };

  STAGE_Q(0, 0); STAGE_Q(0, 1); STAGE_Q(0, 2); STAGE_Q(0, 3);

#pragma unroll 1
  for (int t = 0; t < NK; t++){
    const char* sb = ldsb + (size_t)(t & 1) * 65536;
    const bool pre = (t + 1 < NK);
    f16x8 aF[4], bF[4], aG[4], bF2[4], aF2[4], aG2[4];

    VM(4);                              // gate1: q0,q1(t) landed
    BAR();
    // P0
    if (pre) STAGE_Q(t + 1, 0);
#pragma unroll
    for (int m = 0; m < 4; m++) aF[m] = *(const f16x8*)(sb + wm * 8192 + m * 1024 + rps);
#pragma unroll
    for (int n = 0; n < 4; n++) bF[n] = *(const f16x8*)(sb + 32768 + wn * 4096 + n * 1024 + rps);
    LGKM0();
    __builtin_amdgcn_s_setprio(1);
#pragma unroll
    for (int m = 0; m < 4; m++)
#pragma unroll
      for (int n = 0; n < 4; n++)
        acc[m][n] = __builtin_amdgcn_mfma_f32_16x16x32_f16(aF[m], bF[n], acc[m][n], 0, 0, 0);
    __builtin_amdgcn_s_setprio(0);
    // P1
    if (pre) STAGE_Q(t + 1, 1);
#pragma unroll
    for (int m = 0; m < 4; m++) aG[m] = *(const f16x8*)(sb + wm * 8192 + (m + 4) * 1024 + rps);
    LGKM0();
    __builtin_amdgcn_s_setprio(1);
#pragma unroll
    for (int m = 0; m < 4; m++)
#pragma unroll
      for (int n = 0; n < 4; n++)
        acc[m + 4][n] = __builtin_amdgcn_mfma_f32_16x16x32_f16(aG[m], bF[n], acc[m + 4][n], 0, 0, 0);
    __builtin_amdgcn_s_setprio(0);

    if (pre) { VM(4); } else { VM(0); } // gate2: q2,q3(t) landed
    BAR();
    // P2
    if (pre) STAGE_Q(t + 1, 2);
#pragma unroll
    for (int m = 0; m < 4; m++) aF2[m] = *(const f16x8*)(sb + 16384 + wm * 8192 + m * 1024 + rps);
#pragma unroll
    for (int n = 0; n < 4; n++) bF2[n] = *(const f16x8*)(sb + 49152 + wn * 4096 + n * 1024 + rps);
    LGKM0();
    __builtin_amdgcn_s_setprio(1);
#pragma unroll
    for (int m = 0; m < 4; m++)
#pragma unroll
      for (int n = 0; n < 4; n++)
        acc[m][n] = __builtin_amdgcn_mfma_f32_16x16x32_f16(aF2[m], bF2[n], acc[m][n], 0, 0, 0);
    __builtin_amdgcn_s_setprio(0);
    // P3
    if (pre) STAGE_Q(t + 1, 3);
#pragma unroll
    for (int m = 0; m < 4; m++) aG2[m] = *(const f16x8*)(sb + 16384 + wm * 8192 + (m + 4) * 1024 + rps);
    LGKM0();
    __builtin_amdgcn_s_setprio(1);
#pragma unroll
    for (int m = 0; m < 4; m++)
#pragma unroll
      for (int n = 0; n < 4; n++)
        acc[m + 4][n] = __builtin_amdgcn_mfma_f32_16x16x32_f16(aG2[m], bF2[n], acc[m + 4][n], 0, 0, 0);
    __builtin_amdgcn_s_setprio(0);
  }

#pragma unroll
  for (int m = 0; m < 8; m++)
#pragma unroll
    for (int n = 0; n < 4; n++){
      const int col  = bn * 256 + wn * 64 + n * 16 + l15;
      const int row0 = bm * 256 + wm * 128 + m * 16 + lg * 4;
      if (EPI == 0){
#pragma unroll
        for (int q = 0; q < 4; q++){
          unsigned short hi, lo; split2h(acc[m][n][q], hi, lo);
          const size_t base = (size_t)(row0 + q) * 2048;
          outp[base + col] = hi;
          outp[base + 1024 + col] = lo;
        }
      } else if (EPI == 1){
        const float bgv = bias[col];
        ushort4 h4;
        h4.x = f16b(acc[m][n][0] + bgv); h4.y = f16b(acc[m][n][1] + bgv);
        h4.z = f16b(acc[m][n][2] + bgv); h4.w = f16b(acc[m][n][3] + bgv);
        *(ushort4*)(outp + (size_t)col * 32768 + row0) = h4;
      } else if (EPI == 2){
        ushort4 h4;
        h4.x = f16b(acc[m][n][0]); h4.y = f16b(acc[m][n][1]);
        h4.z = f16b(acc[m][n][2]); h4.w = f16b(acc[m][n][3]);
        *(ushort4*)(outp + (size_t)col * 1024 + row0) = h4;
      } else {                            // EPI 4: single-width row-major y write
#pragma unroll
        for (int q = 0; q < 4; q++)
          outp[(size_t)(row0 + q) * 2048 + col] = f16b(acc[m][n][q]);
      }
    }
}

// ============================================================================
// Fused per-frame kernel: scores (K=2048: yh(k&1023) x [xh|xl]) -> softmax
// -> PV. 512 threads (8 waves 2x4, 2 waves/SIMD). LDS 96 KiB:
//   scores: 2 slots x 32K at [0,64K) (regions Y.k0|Y.k1|X.k0|X.k1, 8K each,
//   XOR-swizzled); softmax sf fp32 reuses [0,64K); P fp16 at [64K,96K);
//   PV F dbuf 2x32K reuses [0,64K) (sf dead after P written).
// PV: 8 h-iterations x 128 f-cols, F double-buffered with counted VM(4);
// end-of-iter BAR excludes the slot-reuse WAR race. Out rows of this frame
// alias this block's own y2 rows in d_out (read fully before overwrite).
// ============================================================================
__global__ __launch_bounds__(512, 2) void k_frame(
    const unsigned short* Y2, const unsigned short* X2,
    const float* __restrict__ v, const unsigned short* __restrict__ FT,
    float* outp)
{
  __shared__ __align__(16) unsigned short lds_u[49152];   // 96 KiB
  char* ldsb = (char*)lds_u;

  const int frame = blockIdx.x;
  const int tid  = threadIdx.x;
  const int w    = tid >> 6;
  const int lane = tid & 63;
  const int wm   = w >> 2;        // 0..1
  const int wn   = w & 3;         // 0..3
  const int l15  = lane & 15;
  const int lg   = lane >> 4;

  // staging chunk map: tid covers one 8K region (128 rows x 32 k), 1 load each
  const int pS = tid >> 3, sS = tid & 7;
  const int qS = sS ^ (pS & 7);
  const int srow = 2 * pS + (qS >> 2);
  const int slg  = qS & 3;
  const unsigned short* yS = Y2 + (size_t)(frame * 128 + srow) * 2048 + slg * 8;
  const unsigned short* xS = X2 + (size_t)(frame * 128 + srow) * 2048 + slg * 8;

  const int sA  = (((l15 & 1) << 2) | lg) ^ ((l15 >> 1) & 7);
  const int rps = (l15 >> 1) * 128 + sA * 16;

  f32x4 acc[4][2];
  f32x4 zero = {0.f, 0.f, 0.f, 0.f};
#pragma unroll
  for (int m = 0; m < 4; m++)
#pragma unroll
    for (int n = 0; n < 2; n++) acc[m][n] = zero;

  auto STAGE_K = [&](int t, int ks){
    char* slot = ldsb + (size_t)(t & 1) * 32768;
    const int kk = t * 64 + ks * 32;
    gload_lds16(yS + (kk & 1023), slot +         ks * 8192 + tid * 16);  // Y: MAP3
    gload_lds16(xS + kk,          slot + 16384 + ks * 8192 + tid * 16);  // X: [xh|xl]
  };

  const int NK = 32;
  STAGE_K(0, 0); STAGE_K(0, 1);

#pragma unroll 1
  for (int t = 0; t < NK; t++){
    const char* sb = ldsb + (size_t)(t & 1) * 32768;
    const bool pre = (t + 1 < NK);
    f16x8 aF[4], bF[2], aF2[4], bF2[2];

    VM(2);                      // gate1: k0(t) landed (k1(t) in flight)
    BAR();
    if (pre) STAGE_K(t + 1, 0);
#pragma unroll
    for (int m = 0; m < 4; m++) aF[m] = *(const f16x8*)(sb + (wm * 4 + m) * 1024 + rps);
#pragma unroll
    for (int n = 0; n < 2; n++) bF[n] = *(const f16x8*)(sb + 16384 + (wn * 2 + n) * 1024 + rps);
    LGKM0();
    __builtin_amdgcn_s_setprio(1);
#pragma unroll
    for (int m = 0; m < 4; m++)
#pragma unroll
      for (int n = 0; n < 2; n++)
        acc[m][n] = __builtin_amdgcn_mfma_f32_16x16x32_f16(aF[m], bF[n], acc[m][n], 0, 0, 0);
    __builtin_amdgcn_s_setprio(0);

    if (pre) { VM(2); } else { VM(0); } // gate2: k1(t) landed
    BAR();
    if (pre) STAGE_K(t + 1, 1);
#pragma unroll
    for (int m = 0; m < 4; m++) aF2[m] = *(const f16x8*)(sb + 8192 + (wm * 4 + m) * 1024 + rps);
#pragma unroll
    for (int n = 0; n < 2; n++) bF2[n] = *(const f16x8*)(sb + 24576 + (wn * 2 + n) * 1024 + rps);
    LGKM0();
    __builtin_amdgcn_s_setprio(1);
#pragma unroll
    for (int m = 0; m < 4; m++)
#pragma unroll
      for (int n = 0; n < 2; n++)
        acc[m][n] = __builtin_amdgcn_mfma_f32_16x16x32_f16(aF2[m], bF2[n], acc[m][n], 0, 0, 0);
    __builtin_amdgcn_s_setprio(0);
  }

  // ---- softmax: acc -> LDS fp32 (rotation swizzle), reduce, P fp16 to LDS ----
  BAR();
  float* sf = (float*)ldsb;                        // 128x128 fp32 = 64KB
#pragma unroll
  for (int m = 0; m < 4; m++)
#pragma unroll
    for (int n = 0; n < 2; n++){
      const int col = wn * 32 + n * 16 + l15;
#pragma unroll
      for (int q = 0; q < 4; q++){
        const int row = wm * 64 + m * 16 + lg * 4 + q;
        sf[row * 128 + ((col + (row & 31) * 4) & 127)] = acc[m][n][q];
      }
    }
  LGKM0(); BAR();
  unsigned short* Pb = (unsigned short*)(ldsb + 65536);  // P: row*256B, chunk-xor
  {
    const float* vr = v + (size_t)frame * 128;
#pragma unroll 1
    for (int i = 0; i < 16; i++){
      const int row = w * 16 + i;
      const float* rp = sf + row * 128;
      const int rot = (row & 31) * 4;
      float a = rp[(lane + rot) & 127]      + vr[lane];
      float b = rp[(lane + 64 + rot) & 127] + vr[lane + 64];
      float mx = fmaxf(a, b);
      for (int o = 32; o; o >>= 1) mx = fmaxf(mx, __shfl_xor(mx, o));
      float ea = __expf(a - mx), eb = __expf(b - mx);
      float s = ea + eb;
      for (int o = 32; o; o >>= 1) s += __shfl_xor(s, o);
      const float inv = 1.0f / s;
      unsigned short* prow = (unsigned short*)((char*)Pb + row * 256);
      const int j0 = lane, j1 = lane + 64;
      *(unsigned short*)((char*)prow + (((j0 >> 3) ^ (row & 15)) * 16) + (j0 & 7) * 2) = f16b(ea * inv);
      *(unsigned short*)((char*)prow + (((j1 >> 3) ^ (row & 15)) * 16) + (j1 & 7) * 2) = f16b(eb * inv);
    }
  }
  LGKM0(); BAR();

  // ---- PV: out[s][f] = sum_j P[s][j] * FT[f][frame*128+j], 8 h x 128 f ----
  char* Fb = ldsb;                                 // reuse [0,64K): 2 x 32K slots
  auto STAGE_F = [&](int h){
    char* slot = Fb + (size_t)(h & 1) * 32768;
#pragma unroll
    for (int j = 0; j < 4; j++){
      const int o = j * 512 + tid;
      const int a = o >> 4, c = o & 15;
      gload_lds16(FT + (size_t)(h * 128 + a) * 32768 + frame * 128 + (c ^ (a & 15)) * 8,
                  slot + (size_t)o * 16);
    }
  };
  STAGE_F(0);

#pragma unroll 1
  for (int h = 0; h < 8; h++){
    if (h + 1 < 8) STAGE_F(h + 1);
    if (h + 1 < 8) { VM(4); } else { VM(0); }  // retire F(h); F(h+1) in flight
    BAR();
    const char* fs = Fb + (size_t)(h & 1) * 32768;
    f16x8 pF[4][4], fF[4][2];
#pragma unroll
    for (int ks = 0; ks < 4; ks++){
#pragma unroll
      for (int m = 0; m < 4; m++){
        const int row = wm * 64 + m * 16 + l15;
        pF[ks][m] = *(const f16x8*)((char*)Pb + row * 256 + (((ks * 4 + lg) ^ (row & 15)) * 16));
      }
#pragma unroll
      for (int n = 0; n < 2; n++){
        const int al = wn * 32 + n * 16 + l15;
        fF[ks][n] = *(const f16x8*)(fs + al * 256 + (((ks * 4 + lg) ^ (al & 15)) * 16));
      }
    }
    LGKM0();
    f32x4 accP[4][2];
#pragma unroll
    for (int m = 0; m < 4; m++)
#pragma unroll
      for (int n = 0; n < 2; n++) accP[m][n] = zero;
    __builtin_amdgcn_s_setprio(1);
#pragma unroll
    for (int ks = 0; ks < 4; ks++)
#pragma unroll
      for (int m = 0; m < 4; m++)
#pragma unroll
        for (int n = 0; n < 2; n++)
          accP[m][n] = __builtin_amdgcn_mfma_f32_16x16x32_f16(pF[ks][m], fF[ks][n], accP[m][n], 0, 0, 0);
    __builtin_amdgcn_s_setprio(0);
#pragma unroll
    for (int m = 0; m < 4; m++)
#pragma unroll
      for (int n = 0; n < 2; n++){
        const int f = h * 128 + wn * 32 + n * 16 + l15;
        const int r0 = wm * 64 + m * 16 + lg * 4;
#pragma unroll
        for (int q = 0; q < 4; q++)
          outp[((size_t)frame * 128 + r0 + q) * 1024 + f] = accP[m][n][q];
      }
    BAR();    // certify all waves' reads of slot (h&1) before its re-stage
  }
}

// ============================================================================
// Merged prep (unchanged).
// ============================================================================
__global__ __launch_bounds__(256) void k_prep(const float* __restrict__ Wa,
                                              const float* __restrict__ Wb,
                                              const float* __restrict__ Wg,
                                              const float* __restrict__ ba,
                                              unsigned short* __restrict__ Wa2,
                                              unsigned short* __restrict__ Wb2,
                                              unsigned short* __restrict__ WgTh,
                                              float* __restrict__ wv){
  const int b = blockIdx.x;
  if (b < 2048){
    const int row = (b < 1024) ? b : (b - 1024);
    const float* src = (b < 1024) ? Wa : Wb;
    unsigned short* dst = (b < 1024) ? Wa2 : Wb2;
    const int c = threadIdx.x * 4;
    float4 val = *(const float4*)(src + (size_t)row * 1024 + c);
    ushort4 h, l;
    split2h(val.x, h.x, l.x); split2h(val.y, h.y, l.y);
    split2h(val.z, h.z, l.z); split2h(val.w, h.w, l.w);
    *(ushort4*)(dst + (size_t)row * 2048 + c) = h;
    *(ushort4*)(dst + (size_t)row * 2048 + 1024 + c) = l;
  } else if (b < 3072){
    const int row = b - 2048;                 // f index
    const int c0 = threadIdx.x * 4;           // a index base
    float4 val = *(const float4*)(Wg + (size_t)row * 1024 + c0);
    float vv[4] = {val.x, val.y, val.z, val.w};
#pragma unroll
    for (int i = 0; i < 4; i++)
      WgTh[(size_t)(c0 + i) * 1024 + row] = f16b(vv[i]);
  } else {
    const int row = (b - 3072) * 4 + (threadIdx.x >> 6);
    const int lane = threadIdx.x & 63;
    float s = 0.f;
#pragma unroll
    for (int j = 0; j < 4; j++){
      const int c = lane * 4 + j * 256;
      float4 wb = *(const float4*)(Wb + (size_t)row * 1024 + c);
      float4 bb = *(const float4*)(ba + c);
      s += wb.x * bb.x + wb.y * bb.y + wb.z * bb.z + wb.w * bb.w;
    }
    for (int o = 32; o; o >>= 1) s += __shfl_xor(s, o);
    if (lane == 0) wv[row] = s;
  }
}

// x split (fp16 hi|lo) + v[row] = x[row,:] . wv. One wave/row, 4/block. grid 2048.
__global__ __launch_bounds__(256) void k_split_x(const float* __restrict__ x,
                                                 unsigned short* __restrict__ x2,
                                                 const float* __restrict__ wv,
                                                 float* __restrict__ v){
  const int w = threadIdx.x >> 6, lane = threadIdx.x & 63;
#pragma unroll
  for (int it = 0; it < 4; it++){
    const int row = blockIdx.x * 4 + w + it * 8192;
    float s = 0.f;
#pragma unroll
    for (int j = 0; j < 4; j++){
      const int c = lane * 4 + j * 256;
      float4 val = *(const float4*)(x + (size_t)row * 1024 + c);
      float4 wvv = *(const float4*)(wv + c);
      ushort4 h, l;
      split2h(val.x, h.x, l.x); split2h(val.y, h.y, l.y);
      split2h(val.z, h.z, l.z); split2h(val.w, h.w, l.w);
      *(ushort4*)(x2 + (size_t)row * 2048 + c) = h;
      *(ushort4*)(x2 + (size_t)row * 2048 + 1024 + c) = l;
      s += val.x * wvv.x + val.y * wvv.y + val.z * wvv.z + val.w * wvv.w;
    }
    for (int o = 32; o; o >>= 1) s += __shfl_xor(s, o);
    if (lane == 0) v[row] = s;
  }
}

// ---------- launcher ----------
extern "C" void kernel_launch(void* const* d_in, const int* in_sizes, int n_in,
                              void* d_out, int out_size, void* d_ws, size_t ws_size,
                              hipStream_t stream) {
  const float* x  = (const float*)d_in[0];
  const float* Wa = (const float*)d_in[2];
  const float* ba = (const float*)d_in[3];
  const float* Wb = (const float*)d_in[4];
  const float* Wg = (const float*)d_in[6];
  const float* bg = (const float*)d_in[7];

  unsigned short* x2   = (unsigned short*)d_ws;            // 32768 x 2048 fp16 [xh|xl]
  unsigned short* Wa2  = x2 + (size_t)32768 * 2048;        // 1024 x 2048
  unsigned short* Wb2  = Wa2 + (size_t)1024 * 2048;        // 1024 x 2048
  unsigned short* WgTh = Wb2 + (size_t)1024 * 2048;        // 1024 x 1024 (Wg^T fp16)
  unsigned short* MTh  = WgTh + (size_t)1024 * 1024;       // 1024 x 1024 (M^T fp16)
  unsigned short* FT   = MTh + (size_t)1024 * 1024;        // 1024 x 32768 (feats^T fp16)
  float* wv = (float*)(FT + (size_t)1024 * 32768);         // 1024
  float* v  = wv + 1024;                                   // 32768
  size_t need = (size_t)((char*)(v + 32768) - (char*)d_ws);
  if (ws_size < need) return;

  unsigned short* y2 = (unsigned short*)d_out;             // yh rows, stride 2048

  k_prep    <<<3328, 256, 0, stream>>>(Wa, Wb, Wg, ba, Wa2, Wb2, WgTh, wv);
  k_split_x <<<2048, 256, 0, stream>>>(x, x2, wv, v);
  // M = Wa*Wb^T, fp16 3-term: [h|l|h] x [h|h|l]; write M^T fp16 (EPI 2). grid 16.
  k_gemm256<1, 2, 48, 2><<<16,  512, 0, stream>>>(Wa2, Wb2, MTh, nullptr, 2048, 2048);
  // featsT = (xh*Wgh + bg)^T fp16 (EPI 1), K=1024. grid 512.
  k_gemm256<0, 0, 16, 1><<<512, 512, 0, stream>>>(x2, WgTh, FT, bg, 2048, 1024);
  // y = xh*Mh, K=1024; single-width row-major write (EPI 4). grid 512.
  k_gemm256<0, 0, 16, 4><<<512, 512, 0, stream>>>(x2, MTh, y2, nullptr, 2048, 1024);
  // scores (K=2048: yh(k&1023) x [xh|xl]) -> softmax -> PV
  k_frame   <<<256,  512, 0, stream>>>(y2, x2, v, FT, (float*)d_out);
}

// Round 12
// 328.656 us; speedup vs baseline: 1.6150x; 1.1565x over previous
//
#include <hip/hip_runtime.h>

typedef _Float16 f16x8 __attribute__((ext_vector_type(8)));
typedef __attribute__((ext_vector_type(4))) float f32x4;

// ---------- helpers ----------
__device__ __forceinline__ unsigned short f16b(float x){
  _Float16 h = (_Float16)x;
  return __builtin_bit_cast(unsigned short, h);
}
__device__ __forceinline__ void split2h(float x, unsigned short &hi, unsigned short &lo){
  _Float16 h = (_Float16)x;
  _Float16 l = (_Float16)(x - (float)h);
  hi = __builtin_bit_cast(unsigned short, h);
  lo = __builtin_bit_cast(unsigned short, l);
}
__device__ __forceinline__ void gload_lds16(const void* g, void* l){
  __builtin_amdgcn_global_load_lds((const __attribute__((address_space(1))) void*)g,
                                   (__attribute__((address_space(3))) void*)l, 16, 0, 0);
}
#define VM(N)    asm volatile("s_waitcnt vmcnt(" #N ")" ::: "memory")
#define LGKM0()  do { asm volatile("s_waitcnt lgkmcnt(0)" ::: "memory"); \
                      __builtin_amdgcn_sched_barrier(0); } while(0)
#define BAR()    do { __builtin_amdgcn_s_barrier(); \
                      __builtin_amdgcn_sched_barrier(0); } while(0)

// K-block remaps: MAP 0 identity; MAP 1 [hi|lo|hi]; MAP 2 [hi|hi|lo]; MAP 3 k mod 1024.
template<int MAP>
__device__ __forceinline__ int kmap(int k){
  if (MAP == 1) return (k < 2048) ? k : (k - 2048);
  if (MAP == 2) return (k < 1024) ? k : (k - 1024);
  if (MAP == 3) return k & 1023;
  return k;
}

// ============================================================================
// 256x256 fp16 GEMM body, BK=64, 512 threads (8 waves 2x4), 2 LDS slots x 64KB.
// R5-measured schedule: 2 barriers/tile; gate1(t) VM(4) retires q0,q1(t);
// gate2(t) VM(4) retires q2,q3(t); each gate precedes its BAR (cross-wave
// certified). XOR-swizzled LDS (verified 0 bank conflicts).
// EPI 1: fp16(acc+bias[col])^T write, stride 32768 (featsT).
// EPI 4: fp16(acc) row-major write, stride 2048 (y path, half-filled).
// EPI 6: fp32(acc)^T write, stride 1024 (M split-K partial).
// ============================================================================
template<int MAPA, int MAPB, int NK, int EPI>
__device__ __forceinline__ void gemm_body(
    const unsigned short* __restrict__ A, const unsigned short* __restrict__ B,
    unsigned short* __restrict__ outp, const float* __restrict__ bias,
    int lda, int ldb, int bm, int bn, char* ldsb)
{
  const int tid  = threadIdx.x;
  const int w    = tid >> 6;
  const int lane = tid & 63;
  const int wm   = w >> 2;              // 0..1
  const int wn   = w & 3;               // 0..3
  const int l15  = lane & 15;
  const int lg   = lane >> 4;

  int srow[2], slg[2];
#pragma unroll
  for (int j = 0; j < 2; j++){
    int o16 = j * 512 + tid;
    int p = o16 >> 3, s = o16 & 7;
    int q = s ^ (p & 7);
    srow[j] = 2 * p + (q >> 2);
    slg[j]  = q & 3;
  }
  const unsigned short* aS0 = A + (size_t)(bm * 256 + srow[0]) * lda + slg[0] * 8;
  const unsigned short* aS1 = A + (size_t)(bm * 256 + srow[1]) * lda + slg[1] * 8;
  const unsigned short* bS0 = B + (size_t)(bn * 256 + srow[0]) * ldb + slg[0] * 8;
  const unsigned short* bS1 = B + (size_t)(bn * 256 + srow[1]) * ldb + slg[1] * 8;

  const int sA   = (((l15 & 1) << 2) | lg) ^ ((l15 >> 1) & 7);
  const int rps  = (l15 >> 1) * 128 + sA * 16;

  f32x4 acc[8][4];
  f32x4 zero = {0.f, 0.f, 0.f, 0.f};
#pragma unroll
  for (int m = 0; m < 8; m++)
#pragma unroll
    for (int n = 0; n < 4; n++) acc[m][n] = zero;

  auto STAGE_Q = [&](int t, int q){
    char* slot = ldsb + (size_t)(t & 1) * 65536;
    const int kbA = kmap<MAPA>(t * 64);
    const int kbB = kmap<MAPB>(t * 64);
    if (q == 0){
      gload_lds16(aS0 + kbA,      slot +         w * 1024);
      gload_lds16(aS1 + kbA,      slot +  8192 + w * 1024);
    } else if (q == 1){
      gload_lds16(bS0 + kbB,      slot + 32768 + w * 1024);
      gload_lds16(bS1 + kbB,      slot + 40960 + w * 1024);
    } else if (q == 2){
      gload_lds16(bS0 + kbB + 32, slot + 49152 + w * 1024);
      gload_lds16(bS1 + kbB + 32, slot + 57344 + w * 1024);
    } else {
      gload_lds16(aS0 + kbA + 32, slot + 16384 + w * 1024);
      gload_lds16(aS1 + kbA + 32, slot + 24576 + w * 1024);
    }
  };

  STAGE_Q(0, 0); STAGE_Q(0, 1); STAGE_Q(0, 2); STAGE_Q(0, 3);

#pragma unroll 1
  for (int t = 0; t < NK; t++){
    const char* sb = ldsb + (size_t)(t & 1) * 65536;
    const bool pre = (t + 1 < NK);
    f16x8 aF[4], bF[4], aG[4], bF2[4], aF2[4], aG2[4];

    VM(4);                              // gate1: q0,q1(t) landed
    BAR();
    if (pre) STAGE_Q(t + 1, 0);
#pragma unroll
    for (int m = 0; m < 4; m++) aF[m] = *(const f16x8*)(sb + wm * 8192 + m * 1024 + rps);
#pragma unroll
    for (int n = 0; n < 4; n++) bF[n] = *(const f16x8*)(sb + 32768 + wn * 4096 + n * 1024 + rps);
    LGKM0();
    __builtin_amdgcn_s_setprio(1);
#pragma unroll
    for (int m = 0; m < 4; m++)
#pragma unroll
      for (int n = 0; n < 4; n++)
        acc[m][n] = __builtin_amdgcn_mfma_f32_16x16x32_f16(aF[m], bF[n], acc[m][n], 0, 0, 0);
    __builtin_amdgcn_s_setprio(0);
    if (pre) STAGE_Q(t + 1, 1);
#pragma unroll
    for (int m = 0; m < 4; m++) aG[m] = *(const f16x8*)(sb + wm * 8192 + (m + 4) * 1024 + rps);
    LGKM0();
    __builtin_amdgcn_s_setprio(1);
#pragma unroll
    for (int m = 0; m < 4; m++)
#pragma unroll
      for (int n = 0; n < 4; n++)
        acc[m + 4][n] = __builtin_amdgcn_mfma_f32_16x16x32_f16(aG[m], bF[n], acc[m + 4][n], 0, 0, 0);
    __builtin_amdgcn_s_setprio(0);

    if (pre) { VM(4); } else { VM(0); } // gate2: q2,q3(t) landed
    BAR();
    if (pre) STAGE_Q(t + 1, 2);
#pragma unroll
    for (int m = 0; m < 4; m++) aF2[m] = *(const f16x8*)(sb + 16384 + wm * 8192 + m * 1024 + rps);
#pragma unroll
    for (int n = 0; n < 4; n++) bF2[n] = *(const f16x8*)(sb + 49152 + wn * 4096 + n * 1024 + rps);
    LGKM0();
    __builtin_amdgcn_s_setprio(1);
#pragma unroll
    for (int m = 0; m < 4; m++)
#pragma unroll
      for (int n = 0; n < 4; n++)
        acc[m][n] = __builtin_amdgcn_mfma_f32_16x16x32_f16(aF2[m], bF2[n], acc[m][n], 0, 0, 0);
    __builtin_amdgcn_s_setprio(0);
    if (pre) STAGE_Q(t + 1, 3);
#pragma unroll
    for (int m = 0; m < 4; m++) aG2[m] = *(const f16x8*)(sb + 16384 + wm * 8192 + (m + 4) * 1024 + rps);
    LGKM0();
    __builtin_amdgcn_s_setprio(1);
#pragma unroll
    for (int m = 0; m < 4; m++)
#pragma unroll
      for (int n = 0; n < 4; n++)
        acc[m + 4][n] = __builtin_amdgcn_mfma_f32_16x16x32_f16(aG2[m], bF2[n], acc[m + 4][n], 0, 0, 0);
    __builtin_amdgcn_s_setprio(0);
  }

#pragma unroll
  for (int m = 0; m < 8; m++)
#pragma unroll
    for (int n = 0; n < 4; n++){
      const int col  = bn * 256 + wn * 64 + n * 16 + l15;
      const int row0 = bm * 256 + wm * 128 + m * 16 + lg * 4;
      if (EPI == 1){
        const float bgv = bias[col];
        ushort4 h4;
        h4.x = f16b(acc[m][n][0] + bgv); h4.y = f16b(acc[m][n][1] + bgv);
        h4.z = f16b(acc[m][n][2] + bgv); h4.w = f16b(acc[m][n][3] + bgv);
        *(ushort4*)(outp + (size_t)col * 32768 + row0) = h4;
      } else if (EPI == 4){
#pragma unroll
        for (int q = 0; q < 4; q++)
          outp[(size_t)(row0 + q) * 2048 + col] = f16b(acc[m][n][q]);
      } else if (EPI == 6){
        float* of = (float*)outp;
#pragma unroll
        for (int q = 0; q < 4; q++)
          of[(size_t)col * 1024 + row0 + q] = acc[m][n][q];
      }
    }
}

// y-GEMM wrapper (EPI 4), grid 512, XCD-swizzled.
template<int MAPA, int MAPB, int NK, int EPI>
__global__ __launch_bounds__(512, 2) void k_gemm256(
    const unsigned short* __restrict__ A, const unsigned short* __restrict__ B,
    unsigned short* __restrict__ outp, const float* __restrict__ bias,
    int lda, int ldb)
{
  __shared__ __align__(16) unsigned short lds_u[65536];
  int bid = blockIdx.x;
  bid = (bid & 7) * (gridDim.x >> 3) + (bid >> 3);
  gemm_body<MAPA, MAPB, NK, EPI>(A, B, outp, bias, lda, ldb, bid >> 2, bid & 3, (char*)lds_u);
}

// Fused launch: blocks [0,512) featsT (EPI 1); [512,560) M split-K partials
// (3 segments x 16 tiles, K=1024 each: hh, lh, hl; EPI 6 fp32). Whole-block
// branch (no divergence); mt blocks hide under featsT's duration.
__global__ __launch_bounds__(512, 2) void k_fused(
    const unsigned short* __restrict__ x2, const unsigned short* __restrict__ WgTh,
    unsigned short* __restrict__ FT, const float* __restrict__ bg,
    const unsigned short* __restrict__ Wa2, const unsigned short* __restrict__ Wb2,
    float* __restrict__ Mpart)
{
  __shared__ __align__(16) unsigned short lds_u[65536];
  const int b = blockIdx.x;
  if (b < 512){
    int bid = (b & 7) * 64 + (b >> 3);
    gemm_body<0, 0, 16, 1>(x2, WgTh, FT, bg, 2048, 1024, bid >> 2, bid & 3, (char*)lds_u);
  } else {
    const int s = (b - 512) >> 4, tile = (b - 512) & 15;
    const unsigned short* Aa = Wa2 + (s == 1 ? 1024 : 0);   // Wal for seg1
    const unsigned short* Bb = Wb2 + (s == 2 ? 1024 : 0);   // Wbl for seg2
    gemm_body<0, 0, 16, 6>(Aa, Bb, (unsigned short*)(Mpart + (size_t)s * 1048576),
                           nullptr, 2048, 2048, tile >> 2, tile & 3, (char*)lds_u);
  }
}

// MTh[i] = fp16(P0[i] + P1[i] + P2[i]); grid 1024 x 256 x float4.
__global__ __launch_bounds__(256) void k_mt_reduce(const float* __restrict__ P,
                                                   unsigned short* __restrict__ MTh){
  const size_t i = ((size_t)blockIdx.x * 256 + threadIdx.x) * 4;
  float4 a = *(const float4*)(P + i);
  float4 b = *(const float4*)(P + 1048576 + i);
  float4 c = *(const float4*)(P + 2097152 + i);
  ushort4 h;
  h.x = f16b(a.x + b.x + c.x); h.y = f16b(a.y + b.y + c.y);
  h.z = f16b(a.z + b.z + c.z); h.w = f16b(a.w + b.w + c.w);
  *(ushort4*)(MTh + i) = h;
}

// ============================================================================
// Fused per-frame kernel, 1024 threads (16 waves, 4 waves/SIMD).
// scores = yh x (xh + xl), K=1024, NK=16 tiles; per tile stage {Y|Xh|Xl}
// (Y read ONCE), both terms MFMA into the same acc. Wave grid 4x4
// (wave-tile 32x32). Ledger: STAGE(t+1)[3 loads] -> VM(3) retires stage(t)
// -> BAR -> 12 ds_read -> LGKM0 -> 16 MFMA -> BAR. WAR: stage(t+1) writes
// slot of t-1, whose reads retired pre-BAR(t-1 end), and stage(t+1) issues
// after that barrier. LDS: slots 2x48K [0,96K); sf fp32 [0,64K) after loop;
// P [96K,128K); PV F dbuf 2x32K [0,64K), VM(2)-gated, same ledger shape.
// Out rows alias this block's own y2 rows (read fully before overwrite).
// ============================================================================
__global__ __launch_bounds__(1024) void k_frame(
    const unsigned short* Y2, const unsigned short* X2,
    const float* __restrict__ v, const unsigned short* __restrict__ FT,
    float* outp)
{
  __shared__ __align__(16) unsigned short lds_u[65536];   // 128 KiB
  char* ldsb = (char*)lds_u;

  const int frame = blockIdx.x;
  const int tid  = threadIdx.x;
  const int w    = tid >> 6;        // 0..15
  const int lane = tid & 63;
  const int wm   = w >> 2;          // 0..3 (row blocks of 32)
  const int wn   = w & 3;           // 0..3 (col blocks of 32)
  const int l15  = lane & 15;
  const int lg   = lane >> 4;

  // stage map: each thread owns one 16B chunk of one 8K region (c), k-half hS
  const int cS = tid & 511, hS = tid >> 9;
  const int pS = cS >> 3, sS = cS & 7;
  const int qS = sS ^ (pS & 7);
  const int srow = 2 * pS + (qS >> 2);
  const int slg  = qS & 3;
  const unsigned short* yS = Y2 + (size_t)(frame * 128 + srow) * 2048 + slg * 8;
  const unsigned short* xS = X2 + (size_t)(frame * 128 + srow) * 2048 + slg * 8;
  const int dY  =         hS * 8192 + cS * 16;
  const int dXh = 16384 + hS * 8192 + cS * 16;
  const int dXl = 32768 + hS * 8192 + cS * 16;

  const int sA  = (((l15 & 1) << 2) | lg) ^ ((l15 >> 1) & 7);
  const int rps = (l15 >> 1) * 128 + sA * 16;

  f32x4 acc[2][2];
  f32x4 zero = {0.f, 0.f, 0.f, 0.f};
#pragma unroll
  for (int m = 0; m < 2; m++)
#pragma unroll
    for (int n = 0; n < 2; n++) acc[m][n] = zero;

  auto STAGE_K = [&](int t){
    char* slot = ldsb + (size_t)(t & 1) * 49152;
    const int kk = t * 64 + hS * 32;
    gload_lds16(yS + kk,        slot + dY);
    gload_lds16(xS + kk,        slot + dXh);
    gload_lds16(xS + 1024 + kk, slot + dXl);
  };

  const int NK = 16;
  STAGE_K(0);

#pragma unroll 1
  for (int t = 0; t < NK; t++){
    const char* sb = ldsb + (size_t)(t & 1) * 49152;
    if (t + 1 < NK){ STAGE_K(t + 1); VM(3); } else { VM(0); }
    BAR();
    f16x8 aF[2][2], bh[2][2], bl[2][2];
#pragma unroll
    for (int h = 0; h < 2; h++){
#pragma unroll
      for (int m = 0; m < 2; m++)
        aF[h][m] = *(const f16x8*)(sb + h * 8192 + (wm * 2 + m) * 1024 + rps);
#pragma unroll
      for (int n = 0; n < 2; n++)
        bh[h][n] = *(const f16x8*)(sb + 16384 + h * 8192 + (wn * 2 + n) * 1024 + rps);
#pragma unroll
      for (int n = 0; n < 2; n++)
        bl[h][n] = *(const f16x8*)(sb + 32768 + h * 8192 + (wn * 2 + n) * 1024 + rps);
    }
    LGKM0();
    __builtin_amdgcn_s_setprio(1);
#pragma unroll
    for (int h = 0; h < 2; h++)
#pragma unroll
      for (int m = 0; m < 2; m++)
#pragma unroll
        for (int n = 0; n < 2; n++){
          acc[m][n] = __builtin_amdgcn_mfma_f32_16x16x32_f16(aF[h][m], bh[h][n], acc[m][n], 0, 0, 0);
          acc[m][n] = __builtin_amdgcn_mfma_f32_16x16x32_f16(aF[h][m], bl[h][n], acc[m][n], 0, 0, 0);
        }
    __builtin_amdgcn_s_setprio(0);
    BAR();
  }

  // ---- softmax: acc -> LDS fp32 (rotation swizzle), reduce, P fp16 to LDS ----
  BAR();
  float* sf = (float*)ldsb;                        // 128x128 fp32 = 64KB
#pragma unroll
  for (int m = 0; m < 2; m++)
#pragma unroll
    for (int n = 0; n < 2; n++){
      const int col = wn * 32 + n * 16 + l15;
#pragma unroll
      for (int q = 0; q < 4; q++){
        const int row = wm * 32 + m * 16 + lg * 4 + q;
        sf[row * 128 + ((col + (row & 31) * 4) & 127)] = acc[m][n][q];
      }
    }
  LGKM0(); BAR();
  unsigned short* Pb = (unsigned short*)(ldsb + 98304);  // P: row*256B, chunk-xor
  {
    const float* vr = v + (size_t)frame * 128;
#pragma unroll 1
    for (int i = 0; i < 8; i++){
      const int row = w * 8 + i;
      const float* rp = sf + row * 128;
      const int rot = (row & 31) * 4;
      float a = rp[(lane + rot) & 127]      + vr[lane];
      float b = rp[(lane + 64 + rot) & 127] + vr[lane + 64];
      float mx = fmaxf(a, b);
      for (int o = 32; o; o >>= 1) mx = fmaxf(mx, __shfl_xor(mx, o));
      float ea = __expf(a - mx), eb = __expf(b - mx);
      float s = ea + eb;
      for (int o = 32; o; o >>= 1) s += __shfl_xor(s, o);
      const float inv = 1.0f / s;
      unsigned short* prow = (unsigned short*)((char*)Pb + row * 256);
      const int j0 = lane, j1 = lane + 64;
      *(unsigned short*)((char*)prow + (((j0 >> 3) ^ (row & 15)) * 16) + (j0 & 7) * 2) = f16b(ea * inv);
      *(unsigned short*)((char*)prow + (((j1 >> 3) ^ (row & 15)) * 16) + (j1 & 7) * 2) = f16b(eb * inv);
    }
  }
  LGKM0(); BAR();

  // ---- PV: out[s][f] = sum_j P[s][j] * FT[f][frame*128+j], 8 h x 128 f ----
  char* Fb = ldsb;                                 // reuse [0,64K): 2 x 32K slots
  auto STAGE_F = [&](int h){
    char* slot = Fb + (size_t)(h & 1) * 32768;
#pragma unroll
    for (int j = 0; j < 2; j++){
      const int o = j * 1024 + tid;
      const int a = o >> 4, c = o & 15;
      gload_lds16(FT + (size_t)(h * 128 + a) * 32768 + frame * 128 + (c ^ (a & 15)) * 8,
                  slot + (size_t)o * 16);
    }
  };
  STAGE_F(0);

#pragma unroll 1
  for (int h = 0; h < 8; h++){
    if (h + 1 < 8){ STAGE_F(h + 1); VM(2); } else { VM(0); }
    BAR();
    const char* fs = Fb + (size_t)(h & 1) * 32768;
    f16x8 pF[4][2], fF[4][2];
#pragma unroll
    for (int ks = 0; ks < 4; ks++){
#pragma unroll
      for (int m = 0; m < 2; m++){
        const int row = wm * 32 + m * 16 + l15;
        pF[ks][m] = *(const f16x8*)((char*)Pb + row * 256 + (((ks * 4 + lg) ^ (row & 15)) * 16));
      }
#pragma unroll
      for (int n = 0; n < 2; n++){
        const int al = wn * 32 + n * 16 + l15;
        fF[ks][n] = *(const f16x8*)(fs + al * 256 + (((ks * 4 + lg) ^ (al & 15)) * 16));
      }
    }
    LGKM0();
    f32x4 accP[2][2];
#pragma unroll
    for (int m = 0; m < 2; m++)
#pragma unroll
      for (int n = 0; n < 2; n++) accP[m][n] = zero;
    __builtin_amdgcn_s_setprio(1);
#pragma unroll
    for (int ks = 0; ks < 4; ks++)
#pragma unroll
      for (int m = 0; m < 2; m++)
#pragma unroll
        for (int n = 0; n < 2; n++)
          accP[m][n] = __builtin_amdgcn_mfma_f32_16x16x32_f16(pF[ks][m], fF[ks][n], accP[m][n], 0, 0, 0);
    __builtin_amdgcn_s_setprio(0);
#pragma unroll
    for (int m = 0; m < 2; m++)
#pragma unroll
      for (int n = 0; n < 2; n++){
        const int f  = h * 128 + wn * 32 + n * 16 + l15;
        const int r0 = wm * 32 + m * 16 + lg * 4;
#pragma unroll
        for (int q = 0; q < 4; q++)
          outp[((size_t)frame * 128 + r0 + q) * 1024 + f] = accP[m][n][q];
      }
    BAR();    // certify all waves' reads of slot (h&1) before its re-stage
  }
}

// ============================================================================
// Merged prep (unchanged).
// ============================================================================
__global__ __launch_bounds__(256) void k_prep(const float* __restrict__ Wa,
                                              const float* __restrict__ Wb,
                                              const float* __restrict__ Wg,
                                              const float* __restrict__ ba,
                                              unsigned short* __restrict__ Wa2,
                                              unsigned short* __restrict__ Wb2,
                                              unsigned short* __restrict__ WgTh,
                                              float* __restrict__ wv){
  const int b = blockIdx.x;
  if (b < 2048){
    const int row = (b < 1024) ? b : (b - 1024);
    const float* src = (b < 1024) ? Wa : Wb;
    unsigned short* dst = (b < 1024) ? Wa2 : Wb2;
    const int c = threadIdx.x * 4;
    float4 val = *(const float4*)(src + (size_t)row * 1024 + c);
    ushort4 h, l;
    split2h(val.x, h.x, l.x); split2h(val.y, h.y, l.y);
    split2h(val.z, h.z, l.z); split2h(val.w, h.w, l.w);
    *(ushort4*)(dst + (size_t)row * 2048 + c) = h;
    *(ushort4*)(dst + (size_t)row * 2048 + 1024 + c) = l;
  } else if (b < 3072){
    const int row = b - 2048;
    const int c0 = threadIdx.x * 4;
    float4 val = *(const float4*)(Wg + (size_t)row * 1024 + c0);
    float vv[4] = {val.x, val.y, val.z, val.w};
#pragma unroll
    for (int i = 0; i < 4; i++)
      WgTh[(size_t)(c0 + i) * 1024 + row] = f16b(vv[i]);
  } else {
    const int row = (b - 3072) * 4 + (threadIdx.x >> 6);
    const int lane = threadIdx.x & 63;
    float s = 0.f;
#pragma unroll
    for (int j = 0; j < 4; j++){
      const int c = lane * 4 + j * 256;
      float4 wb = *(const float4*)(Wb + (size_t)row * 1024 + c);
      float4 bb = *(const float4*)(ba + c);
      s += wb.x * bb.x + wb.y * bb.y + wb.z * bb.z + wb.w * bb.w;
    }
    for (int o = 32; o; o >>= 1) s += __shfl_xor(s, o);
    if (lane == 0) wv[row] = s;
  }
}

// x split (fp16 hi|lo) + v[row] = x[row,:] . wv. One wave/row, 4/block. grid 2048.
__global__ __launch_bounds__(256) void k_split_x(const float* __restrict__ x,
                                                 unsigned short* __restrict__ x2,
                                                 const float* __restrict__ wv,
                                                 float* __restrict__ v){
  const int w = threadIdx.x >> 6, lane = threadIdx.x & 63;
#pragma unroll
  for (int it = 0; it < 4; it++){
    const int row = blockIdx.x * 4 + w + it * 8192;
    float s = 0.f;
#pragma unroll
    for (int j = 0; j < 4; j++){
      const int c = lane * 4 + j * 256;
      float4 val = *(const float4*)(x + (size_t)row * 1024 + c);
      float4 wvv = *(const float4*)(wv + c);
      ushort4 h, l;
      split2h(val.x, h.x, l.x); split2h(val.y, h.y, l.y);
      split2h(val.z, h.z, l.z); split2h(val.w, h.w, l.w);
      *(ushort4*)(x2 + (size_t)row * 2048 + c) = h;
      *(ushort4*)(x2 + (size_t)row * 2048 + 1024 + c) = l;
      s += val.x * wvv.x + val.y * wvv.y + val.z * wvv.z + val.w * wvv.w;
    }
    for (int o = 32; o; o >>= 1) s += __shfl_xor(s, o);
    if (lane == 0) v[row] = s;
  }
}

// ---------- launcher ----------
extern "C" void kernel_launch(void* const* d_in, const int* in_sizes, int n_in,
                              void* d_out, int out_size, void* d_ws, size_t ws_size,
                              hipStream_t stream) {
  const float* x  = (const float*)d_in[0];
  const float* Wa = (const float*)d_in[2];
  const float* ba = (const float*)d_in[3];
  const float* Wb = (const float*)d_in[4];
  const float* Wg = (const float*)d_in[6];
  const float* bg = (const float*)d_in[7];

  unsigned short* x2   = (unsigned short*)d_ws;            // 32768 x 2048 fp16 [xh|xl]
  unsigned short* Wa2  = x2 + (size_t)32768 * 2048;        // 1024 x 2048
  unsigned short* Wb2  = Wa2 + (size_t)1024 * 2048;        // 1024 x 2048
  unsigned short* WgTh = Wb2 + (size_t)1024 * 2048;        // 1024 x 1024 (Wg^T fp16)
  unsigned short* MTh  = WgTh + (size_t)1024 * 1024;       // 1024 x 1024 (M^T fp16)
  unsigned short* FT   = MTh + (size_t)1024 * 1024;        // 1024 x 32768 (feats^T fp16)
  float* Mpart = (float*)(FT + (size_t)1024 * 32768);      // 3 x 1024x1024 fp32
  float* wv = Mpart + (size_t)3 * 1048576;                 // 1024
  float* v  = wv + 1024;                                   // 32768
  size_t need = (size_t)((char*)(v + 32768) - (char*)d_ws);
  if (ws_size < need) return;

  unsigned short* y2 = (unsigned short*)d_out;             // yh rows, stride 2048

  k_prep      <<<3328, 256, 0, stream>>>(Wa, Wb, Wg, ba, Wa2, Wb2, WgTh, wv);
  k_split_x   <<<2048, 256, 0, stream>>>(x, x2, wv, v);
  // featsT (512 blocks) + M split-K partials (48 blocks) in one launch
  k_fused     <<<560,  512, 0, stream>>>(x2, WgTh, FT, bg, Wa2, Wb2, Mpart);
  k_mt_reduce <<<1024, 256, 0, stream>>>(Mpart, MTh);
  // y = xh*Mh, K=1024; single-width row-major write (EPI 4). grid 512.
  k_gemm256<0, 0, 16, 4><<<512, 512, 0, stream>>>(x2, MTh, y2, nullptr, 2048, 1024);
  // scores (K=1024: yh x (xh+xl)) -> softmax -> PV
  k_frame     <<<256, 1024, 0, stream>>>(y2, x2, v, FT, (float*)d_out);
}